// Round 1
// 385.934 us; speedup vs baseline: 1.0521x; 1.0521x over previous
//
#include <hip/hip_runtime.h>
#include <hip/hip_bf16.h>
#include <stdint.h>

// fp32 I/O. Conv3x3, 1x1 projections, and attention run as bf16 MFMA.
// Softmax stats (m,l) and P come from the SAME bf16 MFMA S path (unscaled
// attention -> near-argmax softmax; any S mismatch scales o by exp(dS)).
// Round 7: every MFMA kernel split to >=512 blocks (2 blocks/CU).
// Round 8 (this): attn path rework.
//   - Qt pre-scaled by log2(e); exp -> exp2 everywhere (native v_exp_f32).
//   - attn_pv: i-tile 64, c merged to 256 (S computed once, not per c-tile);
//     Ps[64][64] with XOR swizzle ((i&12)<<3) -> conflict-free store+read
//     (was 8-way on ds_write_b16 = the measured 10M SQ_LDS_BANK_CONFLICT);
//     qa hoisted; rl applied in epilogue instead of per-P-element.
//   - attn_stats: online single-pass m/l, 4 j-segments (512 blocks, 2/CU);
//     rmp/rlp scratch lives in part0 (dead until attn_pv).

constexpr int CINCH = 512;
constexpr int NPIX  = 4096;   // 64*64

typedef __bf16 bf16x8 __attribute__((ext_vector_type(8)));
typedef __bf16 bf16x4 __attribute__((ext_vector_type(4)));
typedef float  f32x4  __attribute__((ext_vector_type(4)));

__device__ __forceinline__ __bf16 f2b(float f) {
    __hip_bfloat16 h = __float2bfloat16(f);
    return *reinterpret_cast<__bf16*>(&h);
}

__device__ __forceinline__ void load_lds16(const void* g, void* l) {
    __builtin_amdgcn_global_load_lds(
        (const __attribute__((address_space(1))) unsigned int*)(uintptr_t)g,
        (__attribute__((address_space(3))) unsigned int*)(uintptr_t)l,
        16, 0, 0);
}

// ---------------------------------------------------------------------------
// Prep A: conv weights fp32 [oc][ic][9] -> Wt bf16 [mod][tap][oc][ic];
// BN scale/shift tables; zero row. grid 2307 x 256.
// ---------------------------------------------------------------------------
__global__ __launch_bounds__(256)
void prep_w(const float* __restrict__ w_r, const float* __restrict__ w_d,
            const float* __restrict__ cb_r, const float* __restrict__ bg_r,
            const float* __restrict__ bb_r, const float* __restrict__ bm_r,
            const float* __restrict__ bv_r,
            const float* __restrict__ cb_d, const float* __restrict__ bg_d,
            const float* __restrict__ bb_d, const float* __restrict__ bm_d,
            const float* __restrict__ bv_d,
            __bf16* __restrict__ Wt, float* __restrict__ scA,
            float* __restrict__ shB, __bf16* __restrict__ zrow)
{
    const int t = threadIdx.x;
    const int blk = blockIdx.x;
    if (blk < 2304) {
        int gid = blk * 1024 + t * 4;
        int mod = gid >= 1179648;
        int o2  = gid - mod * 1179648;
        int tap = o2 >> 17;
        int r   = o2 & 131071;
        int oc  = r >> 9;
        int ic  = r & 511;
        const float* wsrc = mod ? w_d : w_r;
        long base = ((long)(oc * 512 + ic)) * 9 + tap;
        bf16x4 v;
        v.x = f2b(wsrc[base]);
        v.y = f2b(wsrc[base + 9]);
        v.z = f2b(wsrc[base + 18]);
        v.w = f2b(wsrc[base + 27]);
        *(bf16x4*)&Wt[gid] = v;
    } else if (blk == 2304) {
        unsigned short* z = (unsigned short*)zrow;
        z[t] = 0; z[t + 256] = 0;
    } else {
        int mod = blk - 2305;
        const float* cb = mod ? cb_d : cb_r;
        const float* bg = mod ? bg_d : bg_r;
        const float* bb = mod ? bb_d : bb_r;
        const float* bm = mod ? bm_d : bm_r;
        const float* bv = mod ? bv_d : bv_r;
        int oc = t;
        float sc = bg[oc] * rsqrtf(bv[oc] + 1e-5f);
        scA[mod * 256 + oc] = sc;
        shB[mod * 256 + oc] = (cb[oc] - bm[oc]) * sc + bb[oc];
    }
}

// ---------------------------------------------------------------------------
// Prep B: projection weights fp32 -> bf16. Wq/Wk padded to 128 rows (zeros).
// ---------------------------------------------------------------------------
__global__ __launch_bounds__(256)
void prep_gw(const float* __restrict__ qw_r, const float* __restrict__ qw_d,
             const float* __restrict__ kw_r, const float* __restrict__ kw_d,
             const float* __restrict__ vw_r, const float* __restrict__ vw_d,
             const float* __restrict__ uw_r, const float* __restrict__ uw_d,
             __bf16* __restrict__ Wq, __bf16* __restrict__ Wk,
             __bf16* __restrict__ Wv, __bf16* __restrict__ Wu)
{
    int gid = blockIdx.x * 1024 + threadIdx.x * 4;
    __bf16* dst;
    float4 f = make_float4(0.f, 0.f, 0.f, 0.f);
    if (gid < 65536) {
        int mod = gid >> 15, e = gid & 32767;
        dst = Wq + gid;
        if (e < 8192) f = *(const float4*)((mod ? qw_d : qw_r) + e);
    } else if (gid < 131072) {
        int g = gid - 65536;
        int mod = g >> 15, e = g & 32767;
        dst = Wk + g;
        if (e < 8192) f = *(const float4*)((mod ? kw_d : kw_r) + e);
    } else if (gid < 262144) {
        int g = gid - 131072;
        int mod = g >> 16, e = g & 65535;
        dst = Wv + g;
        f = *(const float4*)((mod ? vw_d : vw_r) + e);
    } else {
        int g = gid - 262144;
        int mod = g >> 17, e = g & 131071;
        dst = Wu + g;
        f = *(const float4*)((mod ? uw_d : uw_r) + e);
    }
    bf16x4 o; o.x = f2b(f.x); o.y = f2b(f.y); o.z = f2b(f.z); o.w = f2b(f.w);
    *(bf16x4*)dst = o;
}

// ---------------------------------------------------------------------------
// Prep C: X fp32 [mod][b][512][4096] -> Xp bf16 [modb][4096pix][512ic]
// ---------------------------------------------------------------------------
__global__ __launch_bounds__(256)
void xpose(const float* __restrict__ inr, const float* __restrict__ ind,
           __bf16* __restrict__ Xp)
{
    __shared__ float tile[32][33];
    const int t = threadIdx.x;
    const int p0 = blockIdx.x * 32;
    const int ic0 = blockIdx.y * 32;
    const int mb = blockIdx.z;
    const int mod = mb >> 1, b = mb & 1;
    const float* src = (mod ? ind : inr) + (long)b * CINCH * NPIX;

    int i = t >> 3, j4 = (t & 7) * 4;
    float4 v = *(const float4*)&src[(long)(ic0 + i) * NPIX + p0 + j4];
    tile[i][j4 + 0] = v.x; tile[i][j4 + 1] = v.y;
    tile[i][j4 + 2] = v.z; tile[i][j4 + 3] = v.w;
    __syncthreads();
    int j = t >> 3, i4 = (t & 7) * 4;
    bf16x4 o;
    o.x = f2b(tile[i4 + 0][j]);
    o.y = f2b(tile[i4 + 1][j]);
    o.z = f2b(tile[i4 + 2][j]);
    o.w = f2b(tile[i4 + 3][j]);
    *(bf16x4*)&Xp[((long)mb * NPIX + p0 + j) * 512 + ic0 + i4] = o;
}

// ---------------------------------------------------------------------------
// fp32 [mb][256][4096] -> bf16 transposed [mb][4096][256]. grid (128, 8, 4).
// ---------------------------------------------------------------------------
__global__ __launch_bounds__(256)
void t256(const float* __restrict__ src, __bf16* __restrict__ dst)
{
    __shared__ float tile[32][33];
    const int t = threadIdx.x;
    const int p0 = blockIdx.x * 32;
    const int c0 = blockIdx.y * 32;
    const int mb = blockIdx.z;
    const float* s = src + (long)mb * 256 * NPIX;
    __bf16* d = dst + (long)mb * NPIX * 256;

    int i = t >> 3, j4 = (t & 7) * 4;
    float4 v = *(const float4*)&s[(long)(c0 + i) * NPIX + p0 + j4];
    tile[i][j4 + 0] = v.x; tile[i][j4 + 1] = v.y;
    tile[i][j4 + 2] = v.z; tile[i][j4 + 3] = v.w;
    __syncthreads();
    int j = t >> 3, i4 = (t & 7) * 4;
    bf16x4 o;
    o.x = f2b(tile[i4 + 0][j]); o.y = f2b(tile[i4 + 1][j]);
    o.z = f2b(tile[i4 + 2][j]); o.w = f2b(tile[i4 + 3][j]);
    *(bf16x4*)&d[((long)(p0 + j)) * 256 + c0 + i4] = o;
}

// ---------------------------------------------------------------------------
// Conv3x3 implicit-GEMM MFMA, 64oc x 128pix tile (2 blocks/CU).
// ---------------------------------------------------------------------------
__global__ __launch_bounds__(256)
void conv_mfma(const __bf16* __restrict__ Wt, const __bf16* __restrict__ Xp,
               const __bf16* __restrict__ zrow, const float* __restrict__ scA,
               const float* __restrict__ shB, const float* __restrict__ prr,
               const float* __restrict__ prd, float* __restrict__ conv)
{
    __shared__ __bf16 As[64 * 32];    // 4KB  [oc][32ic]
    __shared__ __bf16 Bs[128 * 32];   // 8KB  [pix][32ic]

    const int t = threadIdx.x;
    const int n0 = blockIdx.x * 128;
    const int m0 = blockIdx.y * 64;
    const int mb = blockIdx.z;
    const int mod = mb >> 1;

    const __bf16* Am = Wt + (long)mod * 9 * 256 * 512;
    const __bf16* Xb = Xp + (long)mb * NPIX * 512;

    const int rowa = t >> 2;          // 0..63
    const int c16  = t & 3;
    char* ldsA  = (char*)As + (t >> 6) * 1024;
    char* ldsB0 = (char*)Bs + (t >> 6) * 1024;
    char* ldsB1 = ldsB0 + 4096;

    const int lane = t & 63, quad = lane >> 4, l15 = lane & 15, w = t >> 6;
    const int nw0 = w * 32;
    const char* abase = (const char*)As + l15 * 64 + quad * 16;
    const char* bbase = (const char*)Bs + (nw0 + l15) * 64 + quad * 16;

    f32x4 acc[4][2];
#pragma unroll
    for (int i = 0; i < 4; ++i)
#pragma unroll
        for (int j = 0; j < 2; ++j) acc[i][j] = (f32x4)0.f;

    for (int tap = 0; tap < 9; ++tap) {
        const int dy = tap / 3 - 1, dx = tap % 3 - 1;
        const __bf16* srcA = Am + (long)tap * 131072 + (long)(m0 + rowa) * 512 + c16 * 8;
        const __bf16* srcB0; const __bf16* srcB1;
        bool v0, v1;
        {
            int n = n0 + rowa;
            int x = n & 63, y = n >> 6;
            v0 = !((dx == -1 && x == 0) || (dx == 1 && x == 63) ||
                   (dy == -1 && y == 0) || (dy == 1 && y == 63));
            srcB0 = v0 ? (Xb + (long)(n + dy * 64 + dx) * 512 + c16 * 8)
                       : (zrow + c16 * 8);
            n += 64; x = n & 63; y = n >> 6;
            v1 = !((dx == -1 && x == 0) || (dx == 1 && x == 63) ||
                   (dy == -1 && y == 0) || (dy == 1 && y == 63));
            srcB1 = v1 ? (Xb + (long)(n + dy * 64 + dx) * 512 + c16 * 8)
                       : (zrow + c16 * 8);
        }

        for (int ic0 = 0; ic0 < 512; ic0 += 32) {
            load_lds16(srcA + ic0, ldsA);
            load_lds16(srcB0 + (v0 ? ic0 : 0), ldsB0);
            load_lds16(srcB1 + (v1 ? ic0 : 0), ldsB1);
            __syncthreads();

            bf16x8 af[4], bfr[2];
#pragma unroll
            for (int i = 0; i < 4; ++i) af[i]  = *(const bf16x8*)(abase + i * 1024);
#pragma unroll
            for (int j = 0; j < 2; ++j) bfr[j] = *(const bf16x8*)(bbase + j * 1024);
#pragma unroll
            for (int i = 0; i < 4; ++i)
#pragma unroll
                for (int j = 0; j < 2; ++j)
                    acc[i][j] = __builtin_amdgcn_mfma_f32_16x16x32_bf16(
                        af[i], bfr[j], acc[i][j], 0, 0, 0);
            __syncthreads();
        }
    }

    const float alpha = (mod ? prd : prr)[0];
    float* outp = conv + (long)mb * 256 * NPIX;
#pragma unroll
    for (int i = 0; i < 4; ++i) {
#pragma unroll
        for (int r = 0; r < 4; ++r) {
            int oc = m0 + 16 * i + quad * 4 + r;
            float sc = scA[mod * 256 + oc];
            float sh = shB[mod * 256 + oc];
            float* orow = outp + (long)oc * NPIX;
#pragma unroll
            for (int j = 0; j < 2; ++j) {
                int n = n0 + nw0 + 16 * j + l15;
                float y = acc[i][j][r] * sc + sh;
                y = (y > 0.f) ? y : alpha * y;
                orow[n] = y;
            }
        }
    }
}

// ---------------------------------------------------------------------------
// 1x1-projection MFMA GEMM. mode 0 output scaled by oscale (log2e for Q).
// ---------------------------------------------------------------------------
__global__ __launch_bounds__(256)
void proj_mfma(const __bf16* __restrict__ Wb, int mstride,
               const __bf16* __restrict__ Bt,
               const float* __restrict__ bias_r, const float* __restrict__ bias_d,
               __bf16* __restrict__ dstT, __bf16* __restrict__ dstV,
               float* __restrict__ dstU,
               const float* __restrict__ resid_r, const float* __restrict__ resid_d,
               int mode, float oscale)
{
    __shared__ __bf16 As[128 * 32];
    __shared__ __bf16 Bs[128 * 32];

    const int t = threadIdx.x;
    const int n0 = blockIdx.x * 128;
    const int m0 = blockIdx.y * 128;
    const int mb = blockIdx.z;
    const int mod = mb >> 1, b = mb & 1;

    const __bf16* Am = Wb + (long)mod * mstride;
    const __bf16* Bm = Bt + (long)mb * (NPIX * 256);
    const float* bias = mod ? bias_d : bias_r;

    const int rowa = t >> 2, c16 = t & 3;
    char* ldsA0 = (char*)As + (t >> 6) * 1024;
    char* ldsA1 = ldsA0 + 4096;
    char* ldsB0 = (char*)Bs + (t >> 6) * 1024;
    char* ldsB1 = ldsB0 + 4096;
    const __bf16* srcA = Am + (long)(m0 + rowa) * 256 + c16 * 8;
    const __bf16* srcB = Bm + (long)(n0 + rowa) * 256 + c16 * 8;

    const int lane = t & 63, quad = lane >> 4, l15 = lane & 15, w = t >> 6;
    const int mw = (w >> 1) * 64, nw = (w & 1) * 64;
    const char* abase = (const char*)As + (mw + l15) * 64 + quad * 16;
    const char* bbase = (const char*)Bs + (nw + l15) * 64 + quad * 16;

    f32x4 acc[4][4];
#pragma unroll
    for (int i = 0; i < 4; ++i)
#pragma unroll
        for (int j = 0; j < 4; ++j) acc[i][j] = (f32x4)0.f;

    for (int kc = 0; kc < 256; kc += 32) {
        load_lds16(srcA + kc, ldsA0);
        load_lds16(srcA + kc + 16384, ldsA1);
        load_lds16(srcB + kc, ldsB0);
        load_lds16(srcB + kc + 16384, ldsB1);
        __syncthreads();

        bf16x8 af[4], bfr[4];
#pragma unroll
        for (int i = 0; i < 4; ++i) af[i]  = *(const bf16x8*)(abase + i * 1024);
#pragma unroll
        for (int j = 0; j < 4; ++j) bfr[j] = *(const bf16x8*)(bbase + j * 1024);
#pragma unroll
        for (int i = 0; i < 4; ++i)
#pragma unroll
            for (int j = 0; j < 4; ++j)
                acc[i][j] = __builtin_amdgcn_mfma_f32_16x16x32_bf16(
                    af[i], bfr[j], acc[i][j], 0, 0, 0);
        __syncthreads();
    }

    if (mode == 0) {
        if (mw == 0) {
            __bf16* dbase = dstT + (long)mb * (NPIX * 32);
#pragma unroll
            for (int fi = 0; fi < 2; ++fi)
#pragma unroll
                for (int r = 0; r < 4; ++r) {
                    int oc = 16 * fi + quad * 4 + r;
                    float bi = bias[oc];
#pragma unroll
                    for (int fj = 0; fj < 4; ++fj) {
                        int n = n0 + nw + 16 * fj + l15;
                        dbase[(long)n * 32 + oc] = f2b((acc[fi][fj][r] + bi) * oscale);
                    }
                }
        }
    } else if (mode == 1) {
        __bf16* dv = dstV + (long)mb * (256 * NPIX);
#pragma unroll
        for (int fi = 0; fi < 4; ++fi)
#pragma unroll
            for (int r = 0; r < 4; ++r) {
                int c = m0 + mw + 16 * fi + quad * 4 + r;
                float bi = bias[c];
                __bf16* row = dv + (long)c * NPIX;
#pragma unroll
                for (int fj = 0; fj < 4; ++fj) {
                    int n = n0 + nw + 16 * fj + l15;
                    row[n] = f2b(acc[fi][fj][r] + bi);
                }
            }
    } else {
        float* du = dstU + (long)mod * 4194304 + (long)b * 2097152;
        const float* rs = (mod ? resid_d : resid_r) + (long)b * 2097152;
#pragma unroll
        for (int fi = 0; fi < 4; ++fi)
#pragma unroll
            for (int r = 0; r < 4; ++r) {
                int oc = m0 + mw + 16 * fi + quad * 4 + r;
                float bi = bias[oc];
                const float* rrow = rs + (long)oc * NPIX;
                float* orow = du + (long)oc * NPIX;
#pragma unroll
                for (int fj = 0; fj < 4; ++fj) {
                    int n = n0 + nw + 16 * fj + l15;
                    orow[n] = acc[fi][fj][r] + bi + rrow[n];
                }
            }
    }
}

// ---------------------------------------------------------------------------
// Online MFMA row stats over a j-SEGMENT [seg*1024, +1024): partial (m, l)
// in log2 domain, single pass. grid (32 i, 4 mbo, 4 seg) = 512 blocks.
// ---------------------------------------------------------------------------
__global__ __launch_bounds__(256)
void attn_stats_mfma(const __bf16* __restrict__ Qt, const __bf16* __restrict__ Kt,
                     float* __restrict__ rmp, float* __restrict__ rlp)
{
    __shared__ __bf16 Qs[128 * 32];
    __shared__ __bf16 Ks[128 * 32];
    __shared__ float redm[2][128];
    __shared__ float redl[2][128];

    const int t  = threadIdx.x;
    const int i0 = blockIdx.x * 128;
    const int mbo = blockIdx.y;
    const int o  = mbo >> 1, b = mbo & 1;
    const int seg = blockIdx.z;
    const int jbase = seg * 1024;
    const int mbK = o * 2 + b, mbQ = (1 - o) * 2 + b;

    const __bf16* Qg = Qt + (long)mbQ * 131072;
    const __bf16* Kg = Kt + (long)mbK * 131072;

    const int lane = t & 63, quad = lane >> 4, l15 = lane & 15, w = t >> 6;
    const int mS = (w >> 1) * 64;
    const int nS = (w & 1) * 64;

    load_lds16((const char*)Qg + (long)i0 * 64 + t * 16, (char*)Qs + w * 1024);
    load_lds16((const char*)Qg + (long)i0 * 64 + 4096 + t * 16,
               (char*)Qs + 4096 + w * 1024);
    __syncthreads();

    bf16x8 qa[4];
#pragma unroll
    for (int fi = 0; fi < 4; ++fi)
        qa[fi] = *(const bf16x8*)((const char*)Qs + (mS + 16 * fi + l15) * 64 + quad * 16);

    const f32x4 zero4 = (f32x4)0.f;
    float m_t[16], l_t[16];
#pragma unroll
    for (int e = 0; e < 16; ++e) { m_t[e] = -3.0e38f; l_t[e] = 0.f; }

    for (int j0 = jbase; j0 < jbase + 1024; j0 += 128) {
        __syncthreads();
        load_lds16((const char*)Kg + (long)j0 * 64 + t * 16, (char*)Ks + w * 1024);
        load_lds16((const char*)Kg + (long)j0 * 64 + 4096 + t * 16,
                   (char*)Ks + 4096 + w * 1024);
        __syncthreads();

        bf16x8 kb[4];
#pragma unroll
        for (int fj = 0; fj < 4; ++fj)
            kb[fj] = *(const bf16x8*)((const char*)Ks + (nS + 16 * fj + l15) * 64 + quad * 16);
#pragma unroll
        for (int fi = 0; fi < 4; ++fi) {
            f32x4 sf[4];
#pragma unroll
            for (int fj = 0; fj < 4; ++fj)
                sf[fj] = __builtin_amdgcn_mfma_f32_16x16x32_bf16(qa[fi], kb[fj], zero4, 0, 0, 0);
#pragma unroll
            for (int r = 0; r < 4; ++r) {
                int e = fi * 4 + r;
                float a = fmaxf(fmaxf(sf[0][r], sf[1][r]), fmaxf(sf[2][r], sf[3][r]));
                float nm = fmaxf(m_t[e], a);
                float s = exp2f(sf[0][r] - nm) + exp2f(sf[1][r] - nm)
                        + exp2f(sf[2][r] - nm) + exp2f(sf[3][r] - nm);
                l_t[e] = l_t[e] * exp2f(m_t[e] - nm) + s;
                m_t[e] = nm;
            }
        }
    }

    // merge across the 16 l15 lanes (each holds a disjoint j-subset)
#pragma unroll
    for (int d = 1; d < 16; d <<= 1)
#pragma unroll
        for (int e = 0; e < 16; ++e) {
            float om = __shfl_xor(m_t[e], d, 64);
            float ol = __shfl_xor(l_t[e], d, 64);
            float nm = fmaxf(m_t[e], om);
            l_t[e] = l_t[e] * exp2f(m_t[e] - nm) + ol * exp2f(om - nm);
            m_t[e] = nm;
        }
    if (l15 == 0) {
#pragma unroll
        for (int fi = 0; fi < 4; ++fi)
#pragma unroll
            for (int r = 0; r < 4; ++r) {
                redm[w & 1][mS + 16 * fi + quad * 4 + r] = m_t[fi * 4 + r];
                redl[w & 1][mS + 16 * fi + quad * 4 + r] = l_t[fi * 4 + r];
            }
    }
    __syncthreads();
    if (t < 128) {
        float m0 = redm[0][t], m1 = redm[1][t];
        float l0 = redl[0][t], l1 = redl[1][t];
        float m = fmaxf(m0, m1);
        float l = l0 * exp2f(m0 - m) + l1 * exp2f(m1 - m);
        rmp[seg * 16384 + mbo * 4096 + i0 + t] = m;
        rlp[seg * 16384 + mbo * 4096 + i0 + t] = l;
    }
}

// ---------------------------------------------------------------------------
// Merge 4-segment stats: m = max, rl = 1/sum(l_s * 2^(m_s-m)). grid 64x256.
// ---------------------------------------------------------------------------
__global__ __launch_bounds__(256)
void stats_merge(const float* __restrict__ rmp, const float* __restrict__ rlp,
                 float* __restrict__ rmb, float* __restrict__ rlb)
{
    int idx = blockIdx.x * 256 + threadIdx.x;
    float m = rmp[idx];
#pragma unroll
    for (int s = 1; s < 4; ++s) m = fmaxf(m, rmp[s * 16384 + idx]);
    float l = 0.f;
#pragma unroll
    for (int s = 0; s < 4; ++s)
        l += rlp[s * 16384 + idx] * exp2f(rmp[s * 16384 + idx] - m);
    rmb[idx] = m;
    rlb[idx] = 1.f / l;
}

// ---------------------------------------------------------------------------
// Fused MFMA PV over a j-SEGMENT, full c=256 per block (S computed ONCE).
// i-tile 64. grid (64 i, 2 seg, 4 mb) = 512 blocks, 2/CU, 48KB LDS.
// Ps[64][64] XOR-swizzled (byte ^= (i&12)<<3): conflict-free store AND read.
// rl applied once in epilogue. P = exp2(S - m) (Qt pre-scaled by log2e).
// ---------------------------------------------------------------------------
__global__ __launch_bounds__(256)
void attn_pv_mfma(const __bf16* __restrict__ Qt, const __bf16* __restrict__ Kt,
                  const __bf16* __restrict__ Vb,
                  float* __restrict__ part0, float* __restrict__ part1,
                  const float* __restrict__ rmb, const float* __restrict__ rlb)
{
    __shared__ __bf16 Qs[64 * 32];        // 4KB  [i][32ch]
    __shared__ __bf16 Ks[64 * 32];        // 4KB  [j][32ch]
    __shared__ __bf16 Vs[2 * 256 * 32];   // 32KB [ks][c][32j]
    __shared__ __bf16 Ps[64 * 64];        // 8KB  [i][64j] swizzled

    const int t  = threadIdx.x;
    const int i0 = blockIdx.x * 64;
    const int seg = blockIdx.y;
    const int mb = blockIdx.z;
    const int o  = mb >> 1, b = mb & 1;
    const int mbK = mb, mbQ = (1 - o) * 2 + b;
    const int jbase = seg * 2048;

    const __bf16* Qg = Qt + (long)mbQ * 131072;
    const __bf16* Kg = Kt + (long)mbK * 131072;
    const __bf16* Vg = Vb + (long)mbK * 1048576;
    const float* rm = rmb + mb * 4096;
    const float* rl = rlb + mb * 4096;

    const int lane = t & 63, quad = lane >> 4, l15 = lane & 15, w = t >> 6;
    const int iS = w * 16;        // this wave's S row block
    const int cw = w * 64;        // this wave's PV c block

    load_lds16((const char*)Qg + (long)i0 * 64 + t * 16, (char*)Qs + w * 1024);

    float mlv[4], rlv[4];
#pragma unroll
    for (int r = 0; r < 4; ++r) mlv[r] = rm[i0 + iS + quad * 4 + r];
#pragma unroll
    for (int fj = 0; fj < 4; ++fj) rlv[fj] = rl[i0 + 16 * fj + l15];

    f32x4 acc[4][4];
#pragma unroll
    for (int i = 0; i < 4; ++i)
#pragma unroll
        for (int j = 0; j < 4; ++j) acc[i][j] = (f32x4)0.f;
    const f32x4 zero4 = (f32x4)0.f;

    __syncthreads();
    const bf16x8 qa = *(const bf16x8*)((const char*)Qs + (iS + l15) * 64 + quad * 16);

    const int clv = w * 16 + (lane >> 2);   // V staging: c within 64-group
    const int jb8 = (lane & 3) * 8;         // V staging: j offset

    for (int j0 = jbase; j0 < jbase + 2048; j0 += 64) {
        __syncthreads();                    // prev-step consumers done
        load_lds16((const char*)Kg + (long)j0 * 64 + t * 16, (char*)Ks + w * 1024);
        __syncthreads();                    // K ready (only K in flight)

        // issue V loads now; latency hides under S + P (drained at next barrier)
#pragma unroll
        for (int ii = 0; ii < 8; ++ii) {
            int ks = ii >> 2;
            int c = (ii & 3) * 64 + clv;
            load_lds16((const char*)Vg + (long)c * 8192 + (long)(j0 + ks * 32 + jb8) * 2,
                       (char*)Vs + ii * 4096 + w * 1024);
        }

        // S = Q K^T for rows [iS,iS+16), cols [0,64)  (one mfma per 16 cols)
        f32x4 sA[4];
#pragma unroll
        for (int fj = 0; fj < 4; ++fj) {
            bf16x8 kb = *(const bf16x8*)((const char*)Ks + (16 * fj + l15) * 64 + quad * 16);
            sA[fj] = __builtin_amdgcn_mfma_f32_16x16x32_bf16(qa, kb, zero4, 0, 0, 0);
        }
        // P = exp2(S - m) -> swizzled Ps (conflict-free b16 stores)
#pragma unroll
        for (int fj = 0; fj < 4; ++fj)
#pragma unroll
            for (int r = 0; r < 4; ++r) {
                int il = iS + quad * 4 + r;
                int boff = (il * 128 + (16 * fj + l15) * 2) ^ ((il & 12) << 3);
                *(__bf16*)((char*)Ps + boff) = f2b(exp2f(sA[fj][r] - mlv[r]));
            }
        __syncthreads();                    // P visible, V staged

#pragma unroll
        for (int ks = 0; ks < 2; ++ks) {
            bf16x8 va[4], pb[4];
#pragma unroll
            for (int fi = 0; fi < 4; ++fi)
                va[fi] = *(const bf16x8*)((const char*)Vs + ks * 16384 +
                                          (cw + 16 * fi + l15) * 64 + quad * 16);
#pragma unroll
            for (int fj = 0; fj < 4; ++fj) {
                int ip = 16 * fj + l15;
                int boff = (ip * 128 + ks * 64 + quad * 16) ^ ((ip & 12) << 3);
                pb[fj] = *(const bf16x8*)((const char*)Ps + boff);
            }
#pragma unroll
            for (int fi = 0; fi < 4; ++fi)
#pragma unroll
                for (int fj = 0; fj < 4; ++fj)
                    acc[fi][fj] = __builtin_amdgcn_mfma_f32_16x16x32_bf16(
                        va[fi], pb[fj], acc[fi][fj], 0, 0, 0);
        }
    }

    // partial store, rl folded here (acc * 1/l)
    float* pg = (seg ? part1 : part0) + (long)mb * 1048576;
#pragma unroll
    for (int fi = 0; fi < 4; ++fi) {
#pragma unroll
        for (int r = 0; r < 4; ++r) {
            int c = cw + 16 * fi + quad * 4 + r;
            float* zr = pg + (long)c * 4096;
#pragma unroll
            for (int fj = 0; fj < 4; ++fj)
                zr[i0 + 16 * fj + l15] = acc[fi][fj][r] * rlv[fj];
        }
    }
}

// ---------------------------------------------------------------------------
// z = gamma*(part0+part1) + conv, transposed bf16 store to Zt[pix][256].
// grid (128, 8, 4).
// ---------------------------------------------------------------------------
__global__ __launch_bounds__(256)
void zred_t(const float* __restrict__ p0, const float* __restrict__ p1,
            const float* __restrict__ convb, __bf16* __restrict__ Zt,
            const float* __restrict__ g_r, const float* __restrict__ g_d)
{
    __shared__ float tile[32][33];
    const int t = threadIdx.x;
    const int pix0 = blockIdx.x * 32;
    const int c0 = blockIdx.y * 32;
    const int mb = blockIdx.z;
    const int o = mb >> 1;
    const float gamma = (o ? g_d : g_r)[0];
    const long base = (long)mb * 1048576;

    int i = t >> 3, j4 = (t & 7) * 4;
    long row = base + (long)(c0 + i) * 4096 + pix0 + j4;
    float4 a = *(const float4*)&p0[row];
    float4 b = *(const float4*)&p1[row];
    float4 cv = *(const float4*)&convb[row];
    tile[i][j4 + 0] = gamma * (a.x + b.x) + cv.x;
    tile[i][j4 + 1] = gamma * (a.y + b.y) + cv.y;
    tile[i][j4 + 2] = gamma * (a.z + b.z) + cv.z;
    tile[i][j4 + 3] = gamma * (a.w + b.w) + cv.w;
    __syncthreads();
    int j = t >> 3, i4 = (t & 7) * 4;
    bf16x4 oq;
    oq.x = f2b(tile[i4 + 0][j]); oq.y = f2b(tile[i4 + 1][j]);
    oq.z = f2b(tile[i4 + 2][j]); oq.w = f2b(tile[i4 + 3][j]);
    *(bf16x4*)&Zt[(long)mb * NPIX * 256 + (long)(pix0 + j) * 256 + c0 + i4] = oq;
}

// ---------------------------------------------------------------------------
// Host launcher
// ---------------------------------------------------------------------------
// ws layout (float slots):
//   conv fp32 [4mb][256][4096] @ 0           (4,194,304)
//   part0 fp32 [4mb][256][4096]@ 4,194,304   (4,194,304)
//     (first 131,072 floats double as rmp/rlp [4seg][4][4096] scratch,
//      consumed by stats_merge BEFORE attn_pv writes part0)
//   rmb  [4mbo][4096]          @ 8,388,608   (16,384)
//   rlb                         @ 8,404,992  (16,384)
//   (old rmp/rlp slots unused)  @ 8,421,376  (65,536)
//   scA  [2][256]              @ 8,486,912   (512)
//   shB  [2][256]              @ 8,487,424   (512)
//   zrow (512 bf16)            @ 8,487,936   (256)
//   Wt   bf16 [2][9][256][512] @ 8,488,192   (1,179,648)
//   Xp   bf16 [4][4096][512]   @ 9,667,840   (4,194,304)  <- part1 after conv
//   Qt   bf16 [4][4096][32]    @ 13,862,144  (262,144)
//   Kt   bf16 [4][4096][32]    @ 14,124,288  (262,144)
//   Vbb  bf16 [4][256][4096]   @ 14,386,432  (2,097,152)
//   Ct   bf16 [4][4096][256]   @ 16,483,584  (2,097,152)
//   Zt   bf16 [4][4096][256]   @ 18,580,736  (2,097,152)
//   Wq   bf16 [2][128][256]    @ 20,677,888  (32,768)
//   Wk   bf16 [2][128][256]    @ 20,710,656  (32,768)
//   Wv   bf16 [2][256][256]    @ 20,743,424  (65,536)
//   Wu   bf16 [2][512][256]    @ 20,808,960  (131,072)
//   total 20,940,032 floats = 83.8 MiB
extern "C" void kernel_launch(void* const* d_in, const int* in_sizes, int n_in,
                              void* d_out, int out_size, void* d_ws, size_t ws_size,
                              hipStream_t stream)
{
    const float* in_rgb = (const float*)d_in[0];
    const float* in_dsm = (const float*)d_in[1];
    auto P = [&](int i) { return (const float*)d_in[i]; };

    float* ws    = (float*)d_ws;
    float* conv  = ws;
    float* part0 = ws + 4194304;
    float* rmb   = ws + 8388608;
    float* rlb   = ws + 8404992;
    float* rmp   = part0;            // [4][4][4096] scratch, dead before pv
    float* rlp   = part0 + 65536;
    float* scA   = ws + 8486912;
    float* shB   = ws + 8487424;
    __bf16* zrow = (__bf16*)(ws + 8487936);
    __bf16* Wt   = (__bf16*)(ws + 8488192);
    __bf16* Xp   = (__bf16*)(ws + 9667840);
    float*  part1 = ws + 9667840;            // aliases Xp (dead after conv)
    __bf16* Qt   = (__bf16*)(ws + 13862144);
    __bf16* Kt   = (__bf16*)(ws + 14124288);
    __bf16* Vbb  = (__bf16*)(ws + 14386432);
    __bf16* Ct   = (__bf16*)(ws + 16483584);
    __bf16* Zt   = (__bf16*)(ws + 18580736);
    __bf16* Wq   = (__bf16*)(ws + 20677888);
    __bf16* Wk   = (__bf16*)(ws + 20710656);
    __bf16* Wv   = (__bf16*)(ws + 20743424);
    __bf16* Wu   = (__bf16*)(ws + 20808960);

    // prep
    prep_w<<<2307, 256, 0, stream>>>(
        P(2), P(18), P(3), P(4), P(5), P(6), P(7),
        P(19), P(20), P(21), P(22), P(23),
        Wt, scA, shB, zrow);
    prep_gw<<<512, 256, 0, stream>>>(
        P(9), P(25), P(11), P(27), P(13), P(29), P(15), P(31),
        Wq, Wk, Wv, Wu);
    xpose<<<dim3(128, 16, 4), 256, 0, stream>>>(in_rgb, in_dsm, Xp);

    // conv3x3 + BN + PReLU (64-oc tiles, 512 blocks)
    conv_mfma<<<dim3(32, 4, 4), 256, 0, stream>>>(
        Wt, Xp, zrow, scA, shB, P(8), P(24), conv);
    t256<<<dim3(128, 8, 4), 256, 0, stream>>>(conv, Ct);

    // q/k/v projections (Q pre-scaled by log2e -> exp2 softmax domain)
    proj_mfma<<<dim3(32, 1, 4), 256, 0, stream>>>(
        Wq, 32768, Ct, P(10), P(26), Qt, nullptr, nullptr, nullptr, nullptr,
        0, 1.4426950408889634f);
    proj_mfma<<<dim3(32, 1, 4), 256, 0, stream>>>(
        Wk, 32768, Ct, P(12), P(28), Kt, nullptr, nullptr, nullptr, nullptr,
        0, 1.0f);
    proj_mfma<<<dim3(32, 2, 4), 256, 0, stream>>>(
        Wv, 65536, Ct, P(14), P(30), nullptr, Vbb, nullptr, nullptr, nullptr,
        1, 1.0f);

    // online softmax stats (j-split x4, 512 blocks) + merge
    attn_stats_mfma<<<dim3(32, 4, 4), 256, 0, stream>>>(Qt, Kt, rmp, rlp);
    stats_merge<<<64, 256, 0, stream>>>(rmp, rlp, rmb, rlb);

    // fused PV (j-split x2 -> raw partials; part1 overwrites dead Xp)
    attn_pv_mfma<<<dim3(64, 2, 4), 256, 0, stream>>>(
        Qt, Kt, Vbb, part0, part1, rmb, rlb);

    // z = gamma*(p0+p1)+conv, transpose + bf16 -> Zt
    zred_t<<<dim3(128, 8, 4), 256, 0, stream>>>(
        part0, part1, conv, Zt, P(17), P(33));

    // up projection + input residual -> fp32 out
    proj_mfma<<<dim3(32, 4, 4), 256, 0, stream>>>(
        Wu, 131072, Zt, P(16), P(32), nullptr, nullptr, (float*)d_out,
        in_rgb, in_dsm, 2, 1.0f);
}

// Round 2
// 384.313 us; speedup vs baseline: 1.0566x; 1.0042x over previous
//
#include <hip/hip_runtime.h>
#include <hip/hip_bf16.h>
#include <stdint.h>

// fp32 I/O. Conv3x3, 1x1 projections, and attention run as bf16 MFMA.
// Softmax stats (m,l) and P come from the SAME bf16 MFMA S path (unscaled
// attention -> near-argmax softmax; any S mismatch scales o by exp(dS)).
// Round 8: attn path rework (exp2 domain, swizzled Ps, online stats).
// Round 9 (this): conv_mfma rework.
//   - wave tile 64oc x 64pix (acc 4x4) = LDS-BW balance point (~100B/cy/wave
//     vs 150B/cy at the old 4x2 tile);
//   - BK=64, double-buffered LDS, stage(next) issued BEFORE compute(cur),
//     one __syncthreads (implicit vmcnt drain) per 64-ic step (was 2 per 32);
//   - XOR-swizzled LDS (slot ^= row&7 on 128B rows), inverse swizzle applied
//     to the GLOBAL source (global_load_lds writes linearly) -> fragment
//     ds_read_b128 spreads 64 lanes uniformly over all 32 banks
//     (was 7.08M SQ_LDS_BANK_CONFLICT from the 64B-row layout);
//   - 128-thread blocks, 512 blocks = 2/CU so barrier drains overlap across
//     co-resident blocks.

constexpr int CINCH = 512;
constexpr int NPIX  = 4096;   // 64*64

typedef __bf16 bf16x8 __attribute__((ext_vector_type(8)));
typedef __bf16 bf16x4 __attribute__((ext_vector_type(4)));
typedef float  f32x4  __attribute__((ext_vector_type(4)));

__device__ __forceinline__ __bf16 f2b(float f) {
    __hip_bfloat16 h = __float2bfloat16(f);
    return *reinterpret_cast<__bf16*>(&h);
}

__device__ __forceinline__ void load_lds16(const void* g, void* l) {
    __builtin_amdgcn_global_load_lds(
        (const __attribute__((address_space(1))) unsigned int*)(uintptr_t)g,
        (__attribute__((address_space(3))) unsigned int*)(uintptr_t)l,
        16, 0, 0);
}

// ---------------------------------------------------------------------------
// Prep A: conv weights fp32 [oc][ic][9] -> Wt bf16 [mod][tap][oc][ic];
// BN scale/shift tables; zero row. grid 2307 x 256.
// ---------------------------------------------------------------------------
__global__ __launch_bounds__(256)
void prep_w(const float* __restrict__ w_r, const float* __restrict__ w_d,
            const float* __restrict__ cb_r, const float* __restrict__ bg_r,
            const float* __restrict__ bb_r, const float* __restrict__ bm_r,
            const float* __restrict__ bv_r,
            const float* __restrict__ cb_d, const float* __restrict__ bg_d,
            const float* __restrict__ bb_d, const float* __restrict__ bm_d,
            const float* __restrict__ bv_d,
            __bf16* __restrict__ Wt, float* __restrict__ scA,
            float* __restrict__ shB, __bf16* __restrict__ zrow)
{
    const int t = threadIdx.x;
    const int blk = blockIdx.x;
    if (blk < 2304) {
        int gid = blk * 1024 + t * 4;
        int mod = gid >= 1179648;
        int o2  = gid - mod * 1179648;
        int tap = o2 >> 17;
        int r   = o2 & 131071;
        int oc  = r >> 9;
        int ic  = r & 511;
        const float* wsrc = mod ? w_d : w_r;
        long base = ((long)(oc * 512 + ic)) * 9 + tap;
        bf16x4 v;
        v.x = f2b(wsrc[base]);
        v.y = f2b(wsrc[base + 9]);
        v.z = f2b(wsrc[base + 18]);
        v.w = f2b(wsrc[base + 27]);
        *(bf16x4*)&Wt[gid] = v;
    } else if (blk == 2304) {
        unsigned short* z = (unsigned short*)zrow;
        z[t] = 0; z[t + 256] = 0;
    } else {
        int mod = blk - 2305;
        const float* cb = mod ? cb_d : cb_r;
        const float* bg = mod ? bg_d : bg_r;
        const float* bb = mod ? bb_d : bb_r;
        const float* bm = mod ? bm_d : bm_r;
        const float* bv = mod ? bv_d : bv_r;
        int oc = t;
        float sc = bg[oc] * rsqrtf(bv[oc] + 1e-5f);
        scA[mod * 256 + oc] = sc;
        shB[mod * 256 + oc] = (cb[oc] - bm[oc]) * sc + bb[oc];
    }
}

// ---------------------------------------------------------------------------
// Prep B: projection weights fp32 -> bf16. Wq/Wk padded to 128 rows (zeros).
// ---------------------------------------------------------------------------
__global__ __launch_bounds__(256)
void prep_gw(const float* __restrict__ qw_r, const float* __restrict__ qw_d,
             const float* __restrict__ kw_r, const float* __restrict__ kw_d,
             const float* __restrict__ vw_r, const float* __restrict__ vw_d,
             const float* __restrict__ uw_r, const float* __restrict__ uw_d,
             __bf16* __restrict__ Wq, __bf16* __restrict__ Wk,
             __bf16* __restrict__ Wv, __bf16* __restrict__ Wu)
{
    int gid = blockIdx.x * 1024 + threadIdx.x * 4;
    __bf16* dst;
    float4 f = make_float4(0.f, 0.f, 0.f, 0.f);
    if (gid < 65536) {
        int mod = gid >> 15, e = gid & 32767;
        dst = Wq + gid;
        if (e < 8192) f = *(const float4*)((mod ? qw_d : qw_r) + e);
    } else if (gid < 131072) {
        int g = gid - 65536;
        int mod = g >> 15, e = g & 32767;
        dst = Wk + g;
        if (e < 8192) f = *(const float4*)((mod ? kw_d : kw_r) + e);
    } else if (gid < 262144) {
        int g = gid - 131072;
        int mod = g >> 16, e = g & 65535;
        dst = Wv + g;
        f = *(const float4*)((mod ? vw_d : vw_r) + e);
    } else {
        int g = gid - 262144;
        int mod = g >> 17, e = g & 131071;
        dst = Wu + g;
        f = *(const float4*)((mod ? uw_d : uw_r) + e);
    }
    bf16x4 o; o.x = f2b(f.x); o.y = f2b(f.y); o.z = f2b(f.z); o.w = f2b(f.w);
    *(bf16x4*)dst = o;
}

// ---------------------------------------------------------------------------
// Prep C: X fp32 [mod][b][512][4096] -> Xp bf16 [modb][4096pix][512ic]
// ---------------------------------------------------------------------------
__global__ __launch_bounds__(256)
void xpose(const float* __restrict__ inr, const float* __restrict__ ind,
           __bf16* __restrict__ Xp)
{
    __shared__ float tile[32][33];
    const int t = threadIdx.x;
    const int p0 = blockIdx.x * 32;
    const int ic0 = blockIdx.y * 32;
    const int mb = blockIdx.z;
    const int mod = mb >> 1, b = mb & 1;
    const float* src = (mod ? ind : inr) + (long)b * CINCH * NPIX;

    int i = t >> 3, j4 = (t & 7) * 4;
    float4 v = *(const float4*)&src[(long)(ic0 + i) * NPIX + p0 + j4];
    tile[i][j4 + 0] = v.x; tile[i][j4 + 1] = v.y;
    tile[i][j4 + 2] = v.z; tile[i][j4 + 3] = v.w;
    __syncthreads();
    int j = t >> 3, i4 = (t & 7) * 4;
    bf16x4 o;
    o.x = f2b(tile[i4 + 0][j]);
    o.y = f2b(tile[i4 + 1][j]);
    o.z = f2b(tile[i4 + 2][j]);
    o.w = f2b(tile[i4 + 3][j]);
    *(bf16x4*)&Xp[((long)mb * NPIX + p0 + j) * 512 + ic0 + i4] = o;
}

// ---------------------------------------------------------------------------
// fp32 [mb][256][4096] -> bf16 transposed [mb][4096][256]. grid (128, 8, 4).
// ---------------------------------------------------------------------------
__global__ __launch_bounds__(256)
void t256(const float* __restrict__ src, __bf16* __restrict__ dst)
{
    __shared__ float tile[32][33];
    const int t = threadIdx.x;
    const int p0 = blockIdx.x * 32;
    const int c0 = blockIdx.y * 32;
    const int mb = blockIdx.z;
    const float* s = src + (long)mb * 256 * NPIX;
    __bf16* d = dst + (long)mb * NPIX * 256;

    int i = t >> 3, j4 = (t & 7) * 4;
    float4 v = *(const float4*)&s[(long)(c0 + i) * NPIX + p0 + j4];
    tile[i][j4 + 0] = v.x; tile[i][j4 + 1] = v.y;
    tile[i][j4 + 2] = v.z; tile[i][j4 + 3] = v.w;
    __syncthreads();
    int j = t >> 3, i4 = (t & 7) * 4;
    bf16x4 o;
    o.x = f2b(tile[i4 + 0][j]); o.y = f2b(tile[i4 + 1][j]);
    o.z = f2b(tile[i4 + 2][j]); o.w = f2b(tile[i4 + 3][j]);
    *(bf16x4*)&d[((long)(p0 + j)) * 256 + c0 + i4] = o;
}

// ---------------------------------------------------------------------------
// Conv3x3 implicit-GEMM MFMA v2.
// Block: 64oc x 128pix, 128 threads (2 waves), each wave 64oc x 64pix (4x4).
// BK=64, double-buffered swizzled LDS, prefetch-before-compute.
// grid (32 pixtiles, 4 octiles, 4 mb) = 512 blocks = 2/CU, 48KB LDS.
// LDS rows are 128B; physical 16B-slot = logical_slot ^ (row&7); the inverse
// swizzle is applied to the global source (global_load_lds writes linearly).
// ---------------------------------------------------------------------------
__global__ __launch_bounds__(128)
void conv_mfma(const __bf16* __restrict__ Wt, const __bf16* __restrict__ Xp,
               const __bf16* __restrict__ zrow, const float* __restrict__ scA,
               const float* __restrict__ shB, const float* __restrict__ prr,
               const float* __restrict__ prd, float* __restrict__ conv)
{
    __shared__ __bf16 As[2 * 64 * 64];     // 16KB: 2 bufs x [64oc][64ic]
    __shared__ __bf16 Bs[2 * 128 * 64];    // 32KB: 2 bufs x [128pix][64ic]

    const int t = threadIdx.x;
    const int n0 = blockIdx.x * 128;
    const int m0 = blockIdx.y * 64;
    const int mb = blockIdx.z;
    const int mod = mb >> 1;

    const __bf16* Am = Wt + (long)mod * (9 * 256 * 512);
    const __bf16* Xb = Xp + (long)mb * NPIX * 512;

    // ---- staging geometry (linear LDS dest, pre-swizzled global source) ----
    const int w    = t >> 6;                   // wave 0..1
    const int srow = t >> 3;                   // 0..15
    const int cS   = (t & 7) ^ (srow & 7);     // swizzled 16B ic-chunk index
    const __bf16* aBase = Am + (long)(m0 + srow) * 512 + cS * 8;
    const __bf16* zsrc  = zrow + cS * 8;
    // B chunk bases + boundary flags (loop-invariant)
    const __bf16* bPtr0; const __bf16* bPtr1; const __bf16* bPtr2;
    const __bf16* bPtr3; const __bf16* bPtr4; const __bf16* bPtr5;
    const __bf16* bPtr6; const __bf16* bPtr7;
    int bFlag[8];
    {
        const __bf16* bp[8];
#pragma unroll
        for (int c = 0; c < 8; ++c) {
            int n = n0 + srow + 16 * c;
            int x = n & 63, y = n >> 6;
            bp[c] = Xb + (long)n * 512 + cS * 8;
            bFlag[c] = (x == 0 ? 1 : 0) | (x == 63 ? 2 : 0) |
                       (y == 0 ? 4 : 0) | (y == 63 ? 8 : 0);
        }
        bPtr0 = bp[0]; bPtr1 = bp[1]; bPtr2 = bp[2]; bPtr3 = bp[3];
        bPtr4 = bp[4]; bPtr5 = bp[5]; bPtr6 = bp[6]; bPtr7 = bp[7];
    }
    char* ldsA = (char*)As + w * 1024;     // + buf*8192  + c*2048
    char* ldsB = (char*)Bs + w * 1024;     // + buf*16384 + c*2048

    // ---- fragment geometry ----
    const int lane = t & 63, quad = lane >> 4, l15 = lane & 15;
    const int nw = w * 64;                 // this wave's pixel offset
    const int soff0 = ((quad ^ (l15 & 7)) << 4);         // kk=0 swizzled slot
    const int soff1 = (((4 | quad) ^ (l15 & 7)) << 4);   // kk=1

    f32x4 acc[4][4];
#pragma unroll
    for (int i = 0; i < 4; ++i)
#pragma unroll
        for (int j = 0; j < 4; ++j) acc[i][j] = (f32x4)0.f;

    auto stage = [&](int buf, int tap, int ic0) {
        const int dy = tap / 3 - 1, dx = tap % 3 - 1;
        const long doff = (long)(dy * 64 + dx) * 512 + ic0;
        const __bf16* sa = aBase + (long)tap * 131072 + ic0;
        char* la = ldsA + buf * 8192;
        load_lds16(sa,         la);
        load_lds16(sa + 8192,  la + 2048);
        load_lds16(sa + 16384, la + 4096);
        load_lds16(sa + 24576, la + 6144);
        const int badmask = (dx == -1 ? 1 : 0) | (dx == 1 ? 2 : 0) |
                            (dy == -1 ? 4 : 0) | (dy == 1 ? 8 : 0);
        char* lb = ldsB + buf * 16384;
        load_lds16((bFlag[0] & badmask) ? zsrc : (bPtr0 + doff), lb);
        load_lds16((bFlag[1] & badmask) ? zsrc : (bPtr1 + doff), lb + 2048);
        load_lds16((bFlag[2] & badmask) ? zsrc : (bPtr2 + doff), lb + 4096);
        load_lds16((bFlag[3] & badmask) ? zsrc : (bPtr3 + doff), lb + 6144);
        load_lds16((bFlag[4] & badmask) ? zsrc : (bPtr4 + doff), lb + 8192);
        load_lds16((bFlag[5] & badmask) ? zsrc : (bPtr5 + doff), lb + 10240);
        load_lds16((bFlag[6] & badmask) ? zsrc : (bPtr6 + doff), lb + 12288);
        load_lds16((bFlag[7] & badmask) ? zsrc : (bPtr7 + doff), lb + 14336);
    };

    // prologue: stage step 0, drain, go
    stage(0, 0, 0);
    __syncthreads();

    int cur = 0;
    for (int step = 0; step < 72; ++step) {
        if (step < 71) {
            const int nxt = step + 1;
            stage(cur ^ 1, nxt >> 3, (nxt & 7) << 6);
        }
        const char* ab = (const char*)As + cur * 8192;
        const char* bb = (const char*)Bs + cur * 16384;
#pragma unroll
        for (int kk = 0; kk < 2; ++kk) {
            const int so = kk ? soff1 : soff0;
            bf16x8 af[4], bfr[4];
#pragma unroll
            for (int i = 0; i < 4; ++i)
                af[i] = *(const bf16x8*)(ab + (16 * i + l15) * 128 + so);
#pragma unroll
            for (int j = 0; j < 4; ++j)
                bfr[j] = *(const bf16x8*)(bb + (nw + 16 * j + l15) * 128 + so);
#pragma unroll
            for (int i = 0; i < 4; ++i)
#pragma unroll
                for (int j = 0; j < 4; ++j)
                    acc[i][j] = __builtin_amdgcn_mfma_f32_16x16x32_bf16(
                        af[i], bfr[j], acc[i][j], 0, 0, 0);
        }
        if (step < 71) __syncthreads();   // drains vmcnt (stage done) + lgkm
        cur ^= 1;
    }

    const float alpha = (mod ? prd : prr)[0];
    float* outp = conv + (long)mb * 256 * NPIX;
#pragma unroll
    for (int i = 0; i < 4; ++i) {
#pragma unroll
        for (int r = 0; r < 4; ++r) {
            int oc = m0 + 16 * i + quad * 4 + r;
            float sc = scA[mod * 256 + oc];
            float sh = shB[mod * 256 + oc];
            float* orow = outp + (long)oc * NPIX;
#pragma unroll
            for (int j = 0; j < 4; ++j) {
                int n = n0 + nw + 16 * j + l15;
                float y = acc[i][j][r] * sc + sh;
                y = (y > 0.f) ? y : alpha * y;
                orow[n] = y;
            }
        }
    }
}

// ---------------------------------------------------------------------------
// 1x1-projection MFMA GEMM. mode 0 output scaled by oscale (log2e for Q).
// ---------------------------------------------------------------------------
__global__ __launch_bounds__(256)
void proj_mfma(const __bf16* __restrict__ Wb, int mstride,
               const __bf16* __restrict__ Bt,
               const float* __restrict__ bias_r, const float* __restrict__ bias_d,
               __bf16* __restrict__ dstT, __bf16* __restrict__ dstV,
               float* __restrict__ dstU,
               const float* __restrict__ resid_r, const float* __restrict__ resid_d,
               int mode, float oscale)
{
    __shared__ __bf16 As[128 * 32];
    __shared__ __bf16 Bs[128 * 32];

    const int t = threadIdx.x;
    const int n0 = blockIdx.x * 128;
    const int m0 = blockIdx.y * 128;
    const int mb = blockIdx.z;
    const int mod = mb >> 1, b = mb & 1;

    const __bf16* Am = Wb + (long)mod * mstride;
    const __bf16* Bm = Bt + (long)mb * (NPIX * 256);
    const float* bias = mod ? bias_d : bias_r;

    const int rowa = t >> 2, c16 = t & 3;
    char* ldsA0 = (char*)As + (t >> 6) * 1024;
    char* ldsA1 = ldsA0 + 4096;
    char* ldsB0 = (char*)Bs + (t >> 6) * 1024;
    char* ldsB1 = ldsB0 + 4096;
    const __bf16* srcA = Am + (long)(m0 + rowa) * 256 + c16 * 8;
    const __bf16* srcB = Bm + (long)(n0 + rowa) * 256 + c16 * 8;

    const int lane = t & 63, quad = lane >> 4, l15 = lane & 15, w = t >> 6;
    const int mw = (w >> 1) * 64, nw = (w & 1) * 64;
    const char* abase = (const char*)As + (mw + l15) * 64 + quad * 16;
    const char* bbase = (const char*)Bs + (nw + l15) * 64 + quad * 16;

    f32x4 acc[4][4];
#pragma unroll
    for (int i = 0; i < 4; ++i)
#pragma unroll
        for (int j = 0; j < 4; ++j) acc[i][j] = (f32x4)0.f;

    for (int kc = 0; kc < 256; kc += 32) {
        load_lds16(srcA + kc, ldsA0);
        load_lds16(srcA + kc + 16384, ldsA1);
        load_lds16(srcB + kc, ldsB0);
        load_lds16(srcB + kc + 16384, ldsB1);
        __syncthreads();

        bf16x8 af[4], bfr[4];
#pragma unroll
        for (int i = 0; i < 4; ++i) af[i]  = *(const bf16x8*)(abase + i * 1024);
#pragma unroll
        for (int j = 0; j < 4; ++j) bfr[j] = *(const bf16x8*)(bbase + j * 1024);
#pragma unroll
        for (int i = 0; i < 4; ++i)
#pragma unroll
            for (int j = 0; j < 4; ++j)
                acc[i][j] = __builtin_amdgcn_mfma_f32_16x16x32_bf16(
                    af[i], bfr[j], acc[i][j], 0, 0, 0);
        __syncthreads();
    }

    if (mode == 0) {
        if (mw == 0) {
            __bf16* dbase = dstT + (long)mb * (NPIX * 32);
#pragma unroll
            for (int fi = 0; fi < 2; ++fi)
#pragma unroll
                for (int r = 0; r < 4; ++r) {
                    int oc = 16 * fi + quad * 4 + r;
                    float bi = bias[oc];
#pragma unroll
                    for (int fj = 0; fj < 4; ++fj) {
                        int n = n0 + nw + 16 * fj + l15;
                        dbase[(long)n * 32 + oc] = f2b((acc[fi][fj][r] + bi) * oscale);
                    }
                }
        }
    } else if (mode == 1) {
        __bf16* dv = dstV + (long)mb * (256 * NPIX);
#pragma unroll
        for (int fi = 0; fi < 4; ++fi)
#pragma unroll
            for (int r = 0; r < 4; ++r) {
                int c = m0 + mw + 16 * fi + quad * 4 + r;
                float bi = bias[c];
                __bf16* row = dv + (long)c * NPIX;
#pragma unroll
                for (int fj = 0; fj < 4; ++fj) {
                    int n = n0 + nw + 16 * fj + l15;
                    row[n] = f2b(acc[fi][fj][r] + bi);
                }
            }
    } else {
        float* du = dstU + (long)mod * 4194304 + (long)b * 2097152;
        const float* rs = (mod ? resid_d : resid_r) + (long)b * 2097152;
#pragma unroll
        for (int fi = 0; fi < 4; ++fi)
#pragma unroll
            for (int r = 0; r < 4; ++r) {
                int oc = m0 + mw + 16 * fi + quad * 4 + r;
                float bi = bias[oc];
                const float* rrow = rs + (long)oc * NPIX;
                float* orow = du + (long)oc * NPIX;
#pragma unroll
                for (int fj = 0; fj < 4; ++fj) {
                    int n = n0 + nw + 16 * fj + l15;
                    orow[n] = acc[fi][fj][r] + bi + rrow[n];
                }
            }
    }
}

// ---------------------------------------------------------------------------
// Online MFMA row stats over a j-SEGMENT [seg*1024, +1024): partial (m, l)
// in log2 domain, single pass. grid (32 i, 4 mbo, 4 seg) = 512 blocks.
// ---------------------------------------------------------------------------
__global__ __launch_bounds__(256)
void attn_stats_mfma(const __bf16* __restrict__ Qt, const __bf16* __restrict__ Kt,
                     float* __restrict__ rmp, float* __restrict__ rlp)
{
    __shared__ __bf16 Qs[128 * 32];
    __shared__ __bf16 Ks[128 * 32];
    __shared__ float redm[2][128];
    __shared__ float redl[2][128];

    const int t  = threadIdx.x;
    const int i0 = blockIdx.x * 128;
    const int mbo = blockIdx.y;
    const int o  = mbo >> 1, b = mbo & 1;
    const int seg = blockIdx.z;
    const int jbase = seg * 1024;
    const int mbK = o * 2 + b, mbQ = (1 - o) * 2 + b;

    const __bf16* Qg = Qt + (long)mbQ * 131072;
    const __bf16* Kg = Kt + (long)mbK * 131072;

    const int lane = t & 63, quad = lane >> 4, l15 = lane & 15, w = t >> 6;
    const int mS = (w >> 1) * 64;
    const int nS = (w & 1) * 64;

    load_lds16((const char*)Qg + (long)i0 * 64 + t * 16, (char*)Qs + w * 1024);
    load_lds16((const char*)Qg + (long)i0 * 64 + 4096 + t * 16,
               (char*)Qs + 4096 + w * 1024);
    __syncthreads();

    bf16x8 qa[4];
#pragma unroll
    for (int fi = 0; fi < 4; ++fi)
        qa[fi] = *(const bf16x8*)((const char*)Qs + (mS + 16 * fi + l15) * 64 + quad * 16);

    const f32x4 zero4 = (f32x4)0.f;
    float m_t[16], l_t[16];
#pragma unroll
    for (int e = 0; e < 16; ++e) { m_t[e] = -3.0e38f; l_t[e] = 0.f; }

    for (int j0 = jbase; j0 < jbase + 1024; j0 += 128) {
        __syncthreads();
        load_lds16((const char*)Kg + (long)j0 * 64 + t * 16, (char*)Ks + w * 1024);
        load_lds16((const char*)Kg + (long)j0 * 64 + 4096 + t * 16,
                   (char*)Ks + 4096 + w * 1024);
        __syncthreads();

        bf16x8 kb[4];
#pragma unroll
        for (int fj = 0; fj < 4; ++fj)
            kb[fj] = *(const bf16x8*)((const char*)Ks + (nS + 16 * fj + l15) * 64 + quad * 16);
#pragma unroll
        for (int fi = 0; fi < 4; ++fi) {
            f32x4 sf[4];
#pragma unroll
            for (int fj = 0; fj < 4; ++fj)
                sf[fj] = __builtin_amdgcn_mfma_f32_16x16x32_bf16(qa[fi], kb[fj], zero4, 0, 0, 0);
#pragma unroll
            for (int r = 0; r < 4; ++r) {
                int e = fi * 4 + r;
                float a = fmaxf(fmaxf(sf[0][r], sf[1][r]), fmaxf(sf[2][r], sf[3][r]));
                float nm = fmaxf(m_t[e], a);
                float s = exp2f(sf[0][r] - nm) + exp2f(sf[1][r] - nm)
                        + exp2f(sf[2][r] - nm) + exp2f(sf[3][r] - nm);
                l_t[e] = l_t[e] * exp2f(m_t[e] - nm) + s;
                m_t[e] = nm;
            }
        }
    }

    // merge across the 16 l15 lanes (each holds a disjoint j-subset)
#pragma unroll
    for (int d = 1; d < 16; d <<= 1)
#pragma unroll
        for (int e = 0; e < 16; ++e) {
            float om = __shfl_xor(m_t[e], d, 64);
            float ol = __shfl_xor(l_t[e], d, 64);
            float nm = fmaxf(m_t[e], om);
            l_t[e] = l_t[e] * exp2f(m_t[e] - nm) + ol * exp2f(om - nm);
            m_t[e] = nm;
        }
    if (l15 == 0) {
#pragma unroll
        for (int fi = 0; fi < 4; ++fi)
#pragma unroll
            for (int r = 0; r < 4; ++r) {
                redm[w & 1][mS + 16 * fi + quad * 4 + r] = m_t[fi * 4 + r];
                redl[w & 1][mS + 16 * fi + quad * 4 + r] = l_t[fi * 4 + r];
            }
    }
    __syncthreads();
    if (t < 128) {
        float m0 = redm[0][t], m1 = redm[1][t];
        float l0 = redl[0][t], l1 = redl[1][t];
        float m = fmaxf(m0, m1);
        float l = l0 * exp2f(m0 - m) + l1 * exp2f(m1 - m);
        rmp[seg * 16384 + mbo * 4096 + i0 + t] = m;
        rlp[seg * 16384 + mbo * 4096 + i0 + t] = l;
    }
}

// ---------------------------------------------------------------------------
// Merge 4-segment stats: m = max, rl = 1/sum(l_s * 2^(m_s-m)). grid 64x256.
// ---------------------------------------------------------------------------
__global__ __launch_bounds__(256)
void stats_merge(const float* __restrict__ rmp, const float* __restrict__ rlp,
                 float* __restrict__ rmb, float* __restrict__ rlb)
{
    int idx = blockIdx.x * 256 + threadIdx.x;
    float m = rmp[idx];
#pragma unroll
    for (int s = 1; s < 4; ++s) m = fmaxf(m, rmp[s * 16384 + idx]);
    float l = 0.f;
#pragma unroll
    for (int s = 0; s < 4; ++s)
        l += rlp[s * 16384 + idx] * exp2f(rmp[s * 16384 + idx] - m);
    rmb[idx] = m;
    rlb[idx] = 1.f / l;
}

// ---------------------------------------------------------------------------
// Fused MFMA PV over a j-SEGMENT, full c=256 per block (S computed ONCE).
// i-tile 64. grid (64 i, 2 seg, 4 mb) = 512 blocks, 2/CU, 48KB LDS.
// Ps[64][64] XOR-swizzled (byte ^= (i&12)<<3): conflict-free store AND read.
// rl applied once in epilogue. P = exp2(S - m) (Qt pre-scaled by log2e).
// ---------------------------------------------------------------------------
__global__ __launch_bounds__(256)
void attn_pv_mfma(const __bf16* __restrict__ Qt, const __bf16* __restrict__ Kt,
                  const __bf16* __restrict__ Vb,
                  float* __restrict__ part0, float* __restrict__ part1,
                  const float* __restrict__ rmb, const float* __restrict__ rlb)
{
    __shared__ __bf16 Qs[64 * 32];        // 4KB  [i][32ch]
    __shared__ __bf16 Ks[64 * 32];        // 4KB  [j][32ch]
    __shared__ __bf16 Vs[2 * 256 * 32];   // 32KB [ks][c][32j]
    __shared__ __bf16 Ps[64 * 64];        // 8KB  [i][64j] swizzled

    const int t  = threadIdx.x;
    const int i0 = blockIdx.x * 64;
    const int seg = blockIdx.y;
    const int mb = blockIdx.z;
    const int o  = mb >> 1, b = mb & 1;
    const int mbK = mb, mbQ = (1 - o) * 2 + b;
    const int jbase = seg * 2048;

    const __bf16* Qg = Qt + (long)mbQ * 131072;
    const __bf16* Kg = Kt + (long)mbK * 131072;
    const __bf16* Vg = Vb + (long)mbK * 1048576;
    const float* rm = rmb + mb * 4096;
    const float* rl = rlb + mb * 4096;

    const int lane = t & 63, quad = lane >> 4, l15 = lane & 15, w = t >> 6;
    const int iS = w * 16;        // this wave's S row block
    const int cw = w * 64;        // this wave's PV c block

    load_lds16((const char*)Qg + (long)i0 * 64 + t * 16, (char*)Qs + w * 1024);

    float mlv[4], rlv[4];
#pragma unroll
    for (int r = 0; r < 4; ++r) mlv[r] = rm[i0 + iS + quad * 4 + r];
#pragma unroll
    for (int fj = 0; fj < 4; ++fj) rlv[fj] = rl[i0 + 16 * fj + l15];

    f32x4 acc[4][4];
#pragma unroll
    for (int i = 0; i < 4; ++i)
#pragma unroll
        for (int j = 0; j < 4; ++j) acc[i][j] = (f32x4)0.f;
    const f32x4 zero4 = (f32x4)0.f;

    __syncthreads();
    const bf16x8 qa = *(const bf16x8*)((const char*)Qs + (iS + l15) * 64 + quad * 16);

    const int clv = w * 16 + (lane >> 2);   // V staging: c within 64-group
    const int jb8 = (lane & 3) * 8;         // V staging: j offset

    for (int j0 = jbase; j0 < jbase + 2048; j0 += 64) {
        __syncthreads();                    // prev-step consumers done
        load_lds16((const char*)Kg + (long)j0 * 64 + t * 16, (char*)Ks + w * 1024);
        __syncthreads();                    // K ready (only K in flight)

        // issue V loads now; latency hides under S + P (drained at next barrier)
#pragma unroll
        for (int ii = 0; ii < 8; ++ii) {
            int ks = ii >> 2;
            int c = (ii & 3) * 64 + clv;
            load_lds16((const char*)Vg + (long)c * 8192 + (long)(j0 + ks * 32 + jb8) * 2,
                       (char*)Vs + ii * 4096 + w * 1024);
        }

        // S = Q K^T for rows [iS,iS+16), cols [0,64)  (one mfma per 16 cols)
        f32x4 sA[4];
#pragma unroll
        for (int fj = 0; fj < 4; ++fj) {
            bf16x8 kb = *(const bf16x8*)((const char*)Ks + (16 * fj + l15) * 64 + quad * 16);
            sA[fj] = __builtin_amdgcn_mfma_f32_16x16x32_bf16(qa, kb, zero4, 0, 0, 0);
        }
        // P = exp2(S - m) -> swizzled Ps (conflict-free b16 stores)
#pragma unroll
        for (int fj = 0; fj < 4; ++fj)
#pragma unroll
            for (int r = 0; r < 4; ++r) {
                int il = iS + quad * 4 + r;
                int boff = (il * 128 + (16 * fj + l15) * 2) ^ ((il & 12) << 3);
                *(__bf16*)((char*)Ps + boff) = f2b(exp2f(sA[fj][r] - mlv[r]));
            }
        __syncthreads();                    // P visible, V staged

#pragma unroll
        for (int ks = 0; ks < 2; ++ks) {
            bf16x8 va[4], pb[4];
#pragma unroll
            for (int fi = 0; fi < 4; ++fi)
                va[fi] = *(const bf16x8*)((const char*)Vs + ks * 16384 +
                                          (cw + 16 * fi + l15) * 64 + quad * 16);
#pragma unroll
            for (int fj = 0; fj < 4; ++fj) {
                int ip = 16 * fj + l15;
                int boff = (ip * 128 + ks * 64 + quad * 16) ^ ((ip & 12) << 3);
                pb[fj] = *(const bf16x8*)((const char*)Ps + boff);
            }
#pragma unroll
            for (int fi = 0; fi < 4; ++fi)
#pragma unroll
                for (int fj = 0; fj < 4; ++fj)
                    acc[fi][fj] = __builtin_amdgcn_mfma_f32_16x16x32_bf16(
                        va[fi], pb[fj], acc[fi][fj], 0, 0, 0);
        }
    }

    // partial store, rl folded here (acc * 1/l)
    float* pg = (seg ? part1 : part0) + (long)mb * 1048576;
#pragma unroll
    for (int fi = 0; fi < 4; ++fi) {
#pragma unroll
        for (int r = 0; r < 4; ++r) {
            int c = cw + 16 * fi + quad * 4 + r;
            float* zr = pg + (long)c * 4096;
#pragma unroll
            for (int fj = 0; fj < 4; ++fj)
                zr[i0 + 16 * fj + l15] = acc[fi][fj][r] * rlv[fj];
        }
    }
}

// ---------------------------------------------------------------------------
// z = gamma*(part0+part1) + conv, transposed bf16 store to Zt[pix][256].
// grid (128, 8, 4).
// ---------------------------------------------------------------------------
__global__ __launch_bounds__(256)
void zred_t(const float* __restrict__ p0, const float* __restrict__ p1,
            const float* __restrict__ convb, __bf16* __restrict__ Zt,
            const float* __restrict__ g_r, const float* __restrict__ g_d)
{
    __shared__ float tile[32][33];
    const int t = threadIdx.x;
    const int pix0 = blockIdx.x * 32;
    const int c0 = blockIdx.y * 32;
    const int mb = blockIdx.z;
    const int o = mb >> 1;
    const float gamma = (o ? g_d : g_r)[0];
    const long base = (long)mb * 1048576;

    int i = t >> 3, j4 = (t & 7) * 4;
    long row = base + (long)(c0 + i) * 4096 + pix0 + j4;
    float4 a = *(const float4*)&p0[row];
    float4 b = *(const float4*)&p1[row];
    float4 cv = *(const float4*)&convb[row];
    tile[i][j4 + 0] = gamma * (a.x + b.x) + cv.x;
    tile[i][j4 + 1] = gamma * (a.y + b.y) + cv.y;
    tile[i][j4 + 2] = gamma * (a.z + b.z) + cv.z;
    tile[i][j4 + 3] = gamma * (a.w + b.w) + cv.w;
    __syncthreads();
    int j = t >> 3, i4 = (t & 7) * 4;
    bf16x4 oq;
    oq.x = f2b(tile[i4 + 0][j]); oq.y = f2b(tile[i4 + 1][j]);
    oq.z = f2b(tile[i4 + 2][j]); oq.w = f2b(tile[i4 + 3][j]);
    *(bf16x4*)&Zt[(long)mb * NPIX * 256 + (long)(pix0 + j) * 256 + c0 + i4] = oq;
}

// ---------------------------------------------------------------------------
// Host launcher
// ---------------------------------------------------------------------------
// ws layout (float slots):
//   conv fp32 [4mb][256][4096] @ 0           (4,194,304)
//   part0 fp32 [4mb][256][4096]@ 4,194,304   (4,194,304)
//     (first 131,072 floats double as rmp/rlp [4seg][4][4096] scratch,
//      consumed by stats_merge BEFORE attn_pv writes part0)
//   rmb  [4mbo][4096]          @ 8,388,608   (16,384)
//   rlb                         @ 8,404,992  (16,384)
//   (old rmp/rlp slots unused)  @ 8,421,376  (65,536)
//   scA  [2][256]              @ 8,486,912   (512)
//   shB  [2][256]              @ 8,487,424   (512)
//   zrow (512 bf16)            @ 8,487,936   (256)
//   Wt   bf16 [2][9][256][512] @ 8,488,192   (1,179,648)
//   Xp   bf16 [4][4096][512]   @ 9,667,840   (4,194,304)  <- part1 after conv
//   Qt   bf16 [4][4096][32]    @ 13,862,144  (262,144)
//   Kt   bf16 [4][4096][32]    @ 14,124,288  (262,144)
//   Vbb  bf16 [4][256][4096]   @ 14,386,432  (2,097,152)
//   Ct   bf16 [4][4096][256]   @ 16,483,584  (2,097,152)
//   Zt   bf16 [4][4096][256]   @ 18,580,736  (2,097,152)
//   Wq   bf16 [2][128][256]    @ 20,677,888  (32,768)
//   Wk   bf16 [2][128][256]    @ 20,710,656  (32,768)
//   Wv   bf16 [2][256][256]    @ 20,743,424  (65,536)
//   Wu   bf16 [2][512][256]    @ 20,808,960  (131,072)
//   total 20,940,032 floats = 83.8 MiB
extern "C" void kernel_launch(void* const* d_in, const int* in_sizes, int n_in,
                              void* d_out, int out_size, void* d_ws, size_t ws_size,
                              hipStream_t stream)
{
    const float* in_rgb = (const float*)d_in[0];
    const float* in_dsm = (const float*)d_in[1];
    auto P = [&](int i) { return (const float*)d_in[i]; };

    float* ws    = (float*)d_ws;
    float* conv  = ws;
    float* part0 = ws + 4194304;
    float* rmb   = ws + 8388608;
    float* rlb   = ws + 8404992;
    float* rmp   = part0;            // [4][4][4096] scratch, dead before pv
    float* rlp   = part0 + 65536;
    float* scA   = ws + 8486912;
    float* shB   = ws + 8487424;
    __bf16* zrow = (__bf16*)(ws + 8487936);
    __bf16* Wt   = (__bf16*)(ws + 8488192);
    __bf16* Xp   = (__bf16*)(ws + 9667840);
    float*  part1 = ws + 9667840;            // aliases Xp (dead after conv)
    __bf16* Qt   = (__bf16*)(ws + 13862144);
    __bf16* Kt   = (__bf16*)(ws + 14124288);
    __bf16* Vbb  = (__bf16*)(ws + 14386432);
    __bf16* Ct   = (__bf16*)(ws + 16483584);
    __bf16* Zt   = (__bf16*)(ws + 18580736);
    __bf16* Wq   = (__bf16*)(ws + 20677888);
    __bf16* Wk   = (__bf16*)(ws + 20710656);
    __bf16* Wv   = (__bf16*)(ws + 20743424);
    __bf16* Wu   = (__bf16*)(ws + 20808960);

    // prep
    prep_w<<<2307, 256, 0, stream>>>(
        P(2), P(18), P(3), P(4), P(5), P(6), P(7),
        P(19), P(20), P(21), P(22), P(23),
        Wt, scA, shB, zrow);
    prep_gw<<<512, 256, 0, stream>>>(
        P(9), P(25), P(11), P(27), P(13), P(29), P(15), P(31),
        Wq, Wk, Wv, Wu);
    xpose<<<dim3(128, 16, 4), 256, 0, stream>>>(in_rgb, in_dsm, Xp);

    // conv3x3 + BN + PReLU (v2: dbuf + swizzle, 128-thread blocks, 512 blocks)
    conv_mfma<<<dim3(32, 4, 4), 128, 0, stream>>>(
        Wt, Xp, zrow, scA, shB, P(8), P(24), conv);
    t256<<<dim3(128, 8, 4), 256, 0, stream>>>(conv, Ct);

    // q/k/v projections (Q pre-scaled by log2e -> exp2 softmax domain)
    proj_mfma<<<dim3(32, 1, 4), 256, 0, stream>>>(
        Wq, 32768, Ct, P(10), P(26), Qt, nullptr, nullptr, nullptr, nullptr,
        0, 1.4426950408889634f);
    proj_mfma<<<dim3(32, 1, 4), 256, 0, stream>>>(
        Wk, 32768, Ct, P(12), P(28), Kt, nullptr, nullptr, nullptr, nullptr,
        0, 1.0f);
    proj_mfma<<<dim3(32, 2, 4), 256, 0, stream>>>(
        Wv, 65536, Ct, P(14), P(30), nullptr, Vbb, nullptr, nullptr, nullptr,
        1, 1.0f);

    // online softmax stats (j-split x4, 512 blocks) + merge
    attn_stats_mfma<<<dim3(32, 4, 4), 256, 0, stream>>>(Qt, Kt, rmp, rlp);
    stats_merge<<<64, 256, 0, stream>>>(rmp, rlp, rmb, rlb);

    // fused PV (j-split x2 -> raw partials; part1 overwrites dead Xp)
    attn_pv_mfma<<<dim3(64, 2, 4), 256, 0, stream>>>(
        Qt, Kt, Vbb, part0, part1, rmb, rlb);

    // z = gamma*(p0+p1)+conv, transpose + bf16 -> Zt
    zred_t<<<dim3(128, 8, 4), 256, 0, stream>>>(
        part0, part1, conv, Zt, P(17), P(33));

    // up projection + input residual -> fp32 out
    proj_mfma<<<dim3(32, 4, 4), 256, 0, stream>>>(
        Wu, 131072, Zt, P(16), P(32), nullptr, nullptr, (float*)d_out,
        in_rgb, in_dsm, 2, 1.0f);
}

// Round 3
// 367.011 us; speedup vs baseline: 1.1064x; 1.0471x over previous
//
#include <hip/hip_runtime.h>
#include <hip/hip_bf16.h>
#include <stdint.h>

// fp32 I/O. Conv3x3, 1x1 projections, and attention run as bf16 MFMA.
// Softmax stats (m,l) and P come from the SAME bf16 MFMA S path (unscaled
// attention -> near-argmax softmax; any S mismatch scales o by exp(dS)).
// Round 8: attn path rework (exp2 domain, swizzled Ps, online stats).
// Round 9: conv swizzle+dbuf (bank conflicts -> 0; time unchanged -> traffic-bound).
// Round 10 (this): conv HALO restructure to cut staged L2/L3 traffic 3.6x.
//   Evidence: r8 (885MB staged, conflicts) and r9 (885MB, no conflicts) both
//   ~89us => staged-byte volume is the limit (~10 TB/s effective fabric).
//   - ic-chunk-outer / tap-inner: 6-row x 64-col pixel halo staged ONCE per
//     64-ic chunk; all 9 taps read it from LDS (B traffic 590->98 MB).
//   - 4-row pixel tiles (256 pix/block): A traffic 288->144 MB. Total 245 MB.
//   - per-lane boundary resolve at ds_read: OOB rows -> LDS zero row.
//   - 1 block/CU (123KB LDS) => counted-vmcnt pipeline (A 3-buf staged 2
//     steps ahead, B 2-buf staged 3 taps ahead, raw s_barrier, no full drain).

constexpr int CINCH = 512;
constexpr int NPIX  = 4096;   // 64*64

typedef __bf16 bf16x8 __attribute__((ext_vector_type(8)));
typedef __bf16 bf16x4 __attribute__((ext_vector_type(4)));
typedef float  f32x4  __attribute__((ext_vector_type(4)));

__device__ __forceinline__ __bf16 f2b(float f) {
    __hip_bfloat16 h = __float2bfloat16(f);
    return *reinterpret_cast<__bf16*>(&h);
}

__device__ __forceinline__ void load_lds16(const void* g, void* l) {
    __builtin_amdgcn_global_load_lds(
        (const __attribute__((address_space(1))) unsigned int*)(uintptr_t)g,
        (__attribute__((address_space(3))) unsigned int*)(uintptr_t)l,
        16, 0, 0);
}

// ---------------------------------------------------------------------------
// Prep A: conv weights fp32 [oc][ic][9] -> Wt bf16 [mod][tap][oc][ic];
// BN scale/shift tables; zero row. grid 2307 x 256.
// ---------------------------------------------------------------------------
__global__ __launch_bounds__(256)
void prep_w(const float* __restrict__ w_r, const float* __restrict__ w_d,
            const float* __restrict__ cb_r, const float* __restrict__ bg_r,
            const float* __restrict__ bb_r, const float* __restrict__ bm_r,
            const float* __restrict__ bv_r,
            const float* __restrict__ cb_d, const float* __restrict__ bg_d,
            const float* __restrict__ bb_d, const float* __restrict__ bm_d,
            const float* __restrict__ bv_d,
            __bf16* __restrict__ Wt, float* __restrict__ scA,
            float* __restrict__ shB, __bf16* __restrict__ zrow)
{
    const int t = threadIdx.x;
    const int blk = blockIdx.x;
    if (blk < 2304) {
        int gid = blk * 1024 + t * 4;
        int mod = gid >= 1179648;
        int o2  = gid - mod * 1179648;
        int tap = o2 >> 17;
        int r   = o2 & 131071;
        int oc  = r >> 9;
        int ic  = r & 511;
        const float* wsrc = mod ? w_d : w_r;
        long base = ((long)(oc * 512 + ic)) * 9 + tap;
        bf16x4 v;
        v.x = f2b(wsrc[base]);
        v.y = f2b(wsrc[base + 9]);
        v.z = f2b(wsrc[base + 18]);
        v.w = f2b(wsrc[base + 27]);
        *(bf16x4*)&Wt[gid] = v;
    } else if (blk == 2304) {
        unsigned short* z = (unsigned short*)zrow;
        z[t] = 0; z[t + 256] = 0;
    } else {
        int mod = blk - 2305;
        const float* cb = mod ? cb_d : cb_r;
        const float* bg = mod ? bg_d : bg_r;
        const float* bb = mod ? bb_d : bb_r;
        const float* bm = mod ? bm_d : bm_r;
        const float* bv = mod ? bv_d : bv_r;
        int oc = t;
        float sc = bg[oc] * rsqrtf(bv[oc] + 1e-5f);
        scA[mod * 256 + oc] = sc;
        shB[mod * 256 + oc] = (cb[oc] - bm[oc]) * sc + bb[oc];
    }
}

// ---------------------------------------------------------------------------
// Prep B: projection weights fp32 -> bf16. Wq/Wk padded to 128 rows (zeros).
// ---------------------------------------------------------------------------
__global__ __launch_bounds__(256)
void prep_gw(const float* __restrict__ qw_r, const float* __restrict__ qw_d,
             const float* __restrict__ kw_r, const float* __restrict__ kw_d,
             const float* __restrict__ vw_r, const float* __restrict__ vw_d,
             const float* __restrict__ uw_r, const float* __restrict__ uw_d,
             __bf16* __restrict__ Wq, __bf16* __restrict__ Wk,
             __bf16* __restrict__ Wv, __bf16* __restrict__ Wu)
{
    int gid = blockIdx.x * 1024 + threadIdx.x * 4;
    __bf16* dst;
    float4 f = make_float4(0.f, 0.f, 0.f, 0.f);
    if (gid < 65536) {
        int mod = gid >> 15, e = gid & 32767;
        dst = Wq + gid;
        if (e < 8192) f = *(const float4*)((mod ? qw_d : qw_r) + e);
    } else if (gid < 131072) {
        int g = gid - 65536;
        int mod = g >> 15, e = g & 32767;
        dst = Wk + g;
        if (e < 8192) f = *(const float4*)((mod ? kw_d : kw_r) + e);
    } else if (gid < 262144) {
        int g = gid - 131072;
        int mod = g >> 16, e = g & 65535;
        dst = Wv + g;
        f = *(const float4*)((mod ? vw_d : vw_r) + e);
    } else {
        int g = gid - 262144;
        int mod = g >> 17, e = g & 131071;
        dst = Wu + g;
        f = *(const float4*)((mod ? uw_d : uw_r) + e);
    }
    bf16x4 o; o.x = f2b(f.x); o.y = f2b(f.y); o.z = f2b(f.z); o.w = f2b(f.w);
    *(bf16x4*)dst = o;
}

// ---------------------------------------------------------------------------
// Prep C: X fp32 [mod][b][512][4096] -> Xp bf16 [modb][4096pix][512ic]
// ---------------------------------------------------------------------------
__global__ __launch_bounds__(256)
void xpose(const float* __restrict__ inr, const float* __restrict__ ind,
           __bf16* __restrict__ Xp)
{
    __shared__ float tile[32][33];
    const int t = threadIdx.x;
    const int p0 = blockIdx.x * 32;
    const int ic0 = blockIdx.y * 32;
    const int mb = blockIdx.z;
    const int mod = mb >> 1, b = mb & 1;
    const float* src = (mod ? ind : inr) + (long)b * CINCH * NPIX;

    int i = t >> 3, j4 = (t & 7) * 4;
    float4 v = *(const float4*)&src[(long)(ic0 + i) * NPIX + p0 + j4];
    tile[i][j4 + 0] = v.x; tile[i][j4 + 1] = v.y;
    tile[i][j4 + 2] = v.z; tile[i][j4 + 3] = v.w;
    __syncthreads();
    int j = t >> 3, i4 = (t & 7) * 4;
    bf16x4 o;
    o.x = f2b(tile[i4 + 0][j]);
    o.y = f2b(tile[i4 + 1][j]);
    o.z = f2b(tile[i4 + 2][j]);
    o.w = f2b(tile[i4 + 3][j]);
    *(bf16x4*)&Xp[((long)mb * NPIX + p0 + j) * 512 + ic0 + i4] = o;
}

// ---------------------------------------------------------------------------
// fp32 [mb][256][4096] -> bf16 transposed [mb][4096][256]. grid (128, 8, 4).
// ---------------------------------------------------------------------------
__global__ __launch_bounds__(256)
void t256(const float* __restrict__ src, __bf16* __restrict__ dst)
{
    __shared__ float tile[32][33];
    const int t = threadIdx.x;
    const int p0 = blockIdx.x * 32;
    const int c0 = blockIdx.y * 32;
    const int mb = blockIdx.z;
    const float* s = src + (long)mb * 256 * NPIX;
    __bf16* d = dst + (long)mb * NPIX * 256;

    int i = t >> 3, j4 = (t & 7) * 4;
    float4 v = *(const float4*)&s[(long)(c0 + i) * NPIX + p0 + j4];
    tile[i][j4 + 0] = v.x; tile[i][j4 + 1] = v.y;
    tile[i][j4 + 2] = v.z; tile[i][j4 + 3] = v.w;
    __syncthreads();
    int j = t >> 3, i4 = (t & 7) * 4;
    bf16x4 o;
    o.x = f2b(tile[i4 + 0][j]); o.y = f2b(tile[i4 + 1][j]);
    o.z = f2b(tile[i4 + 2][j]); o.w = f2b(tile[i4 + 3][j]);
    *(bf16x4*)&d[((long)(p0 + j)) * 256 + c0 + i4] = o;
}

// ---------------------------------------------------------------------------
// Conv3x3 implicit-GEMM MFMA v3 (halo).
// Block: 64oc x 256pix (4 y-rows), 256 threads (4 waves), wave = 64oc x 64pix
// (one y-row), acc 4x4. ic-chunk-outer (8 chunks of 64), tap-inner (9).
// B halo: 6 y-rows x 64 x per chunk, staged once, all 9 taps from LDS.
// A: [64oc][64ic] per (chunk,tap), triple-buffered, staged 2 steps ahead.
// B: double-buffered, staged at tap 6 for chunk+1 (3-step lead).
// Counted vmcnt + raw s_barrier (no full drains). 1 block/CU (123KB LDS).
// Swizzle: 128B rows, phys 16B-slot = logical ^ (row&7); inverse applied to
// the global source (global_load_lds writes linearly). OOB taps -> zero row.
// grid (16 pixtiles, 4 octiles, 4 mb) = 256 blocks.
// ---------------------------------------------------------------------------
__global__ __launch_bounds__(256)
void conv_mfma(const __bf16* __restrict__ Wt, const __bf16* __restrict__ Xp,
               const __bf16* __restrict__ zrow, const float* __restrict__ scA,
               const float* __restrict__ shB, const float* __restrict__ prr,
               const float* __restrict__ prd, float* __restrict__ conv)
{
    __shared__ __bf16 As[3 * 64 * 64];      // 24 KB: 3 bufs x [64oc][64ic]
    __shared__ __bf16 Bs[2 * 385 * 64];     // 96.25 KB: 2 bufs x [385 rows][64ic]
                                            // rows 0..383 = halo (6y x 64x), 384 = zeros

    const int t = threadIdx.x;
    const int y0 = blockIdx.x * 4;          // tile pixel-rows y0..y0+3
    const int m0 = blockIdx.y * 64;
    const int mb = blockIdx.z;
    const int mod = mb >> 1;

    const __bf16* Am = Wt + (long)mod * (9 * 256 * 512);
    const __bf16* Xb = Xp + (long)mb * NPIX * 512;

    const int lane = t & 63, quad = lane >> 4, l15 = lane & 15, w = t >> 6;

    // zero rows (row 384 of each B buffer)
    if (t < 16)
        *(f32x4*)((char*)Bs + (t >> 3) * 49280 + 49152 + (t & 7) * 16) = (f32x4)0.f;
    asm volatile("s_waitcnt lgkmcnt(0)" ::: "memory");

    // ---- staging (linear LDS dest = uniform base + lane*16; swizzled src) ----
    auto stage_a = [&](int buf, int tap, int cc) {
#pragma unroll
        for (int k = 0; k < 2; ++k) {
            int r  = w * 16 + k * 8 + (lane >> 3);
            int sl = (lane & 7) ^ (r & 7);
            const __bf16* src = Am + (long)tap * 131072 + (long)(m0 + r) * 512
                              + cc * 64 + sl * 8;
            load_lds16(src, (char*)As + buf * 8192 + (w * 16 + k * 8) * 128);
        }
    };
    auto stage_b = [&](int buf, int cc) {
#pragma unroll
        for (int k = 0; k < 12; ++k) {
            int r  = w * 96 + k * 8 + (lane >> 3);
            int sl = (lane & 7) ^ (r & 7);
            int hr = r >> 6, xx = r & 63;
            int gy = y0 + hr - 1;
            const __bf16* src = ((unsigned)gy < 64u)
                ? Xb + (long)(gy * 64 + xx) * 512 + cc * 64 + sl * 8
                : zrow + sl * 8;
            load_lds16(src, (char*)Bs + buf * 49280 + (w * 96 + k * 8) * 128);
        }
    };

    f32x4 acc[4][4];
#pragma unroll
    for (int i = 0; i < 4; ++i)
#pragma unroll
        for (int j = 0; j < 4; ++j) acc[i][j] = (f32x4)0.f;

    // prologue: B(chunk0), A(step0), A(step1) in flight
    stage_b(0, 0);
    stage_a(0, 0, 0);
    stage_a(1, 1, 0);

    const int soffA0 = ((quad ^ (l15 & 7)) << 4);
    const int soffA1 = (((4 | quad) ^ (l15 & 7)) << 4);

    for (int c = 0; c < 8; ++c) {
        for (int tp = 0; tp < 9; ++tp) {
            const int s = c * 9 + tp;
            // counted wait: A(s) [and B(c) at tp==0] complete, newer stay in flight
            if (s == 71)                  { asm volatile("s_waitcnt vmcnt(0)" ::: "memory"); }
            else if (tp >= 7 && c < 7)    { asm volatile("s_waitcnt vmcnt(14)" ::: "memory"); }
            else                          { asm volatile("s_waitcnt vmcnt(2)" ::: "memory"); }
            __builtin_amdgcn_sched_barrier(0);
            __builtin_amdgcn_s_barrier();
            __builtin_amdgcn_sched_barrier(0);

            // prefetch A two steps ahead
            if (s + 2 < 72) {
                int c2 = (tp + 2 >= 9) ? c + 1 : c;
                int t2 = (tp + 2 >= 9) ? tp - 7 : tp + 2;
                int b2 = (s + 2) % 3;
                stage_a(b2, t2, c2);
            }
            __builtin_amdgcn_sched_barrier(0);
            // prefetch B one chunk ahead, 3 taps early
            if (tp == 6 && c < 7) stage_b((c + 1) & 1, c + 1);
            __builtin_amdgcn_sched_barrier(0);

            // compute tap tp on chunk c
            const char* ab = (const char*)As + (s % 3) * 8192;
            const char* bb = (const char*)Bs + (c & 1) * 49280;
            const int dy = tp / 3 - 1, dx = tp % 3 - 1;
            const int hr = w + 1 + dy;
            int rb[4];
#pragma unroll
            for (int fj = 0; fj < 4; ++fj) {
                int x = fj * 16 + l15 + dx;
                rb[fj] = ((unsigned)x < 64u) ? hr * 64 + x : 384;
            }
#pragma unroll
            for (int kk = 0; kk < 2; ++kk) {
                const int slq = kk * 4 + quad;
                bf16x8 af[4], bfr[4];
#pragma unroll
                for (int i = 0; i < 4; ++i)
                    af[i] = *(const bf16x8*)(ab + (16 * i + l15) * 128
                                             + (kk ? soffA1 : soffA0));
#pragma unroll
                for (int fj = 0; fj < 4; ++fj)
                    bfr[fj] = *(const bf16x8*)(bb + rb[fj] * 128
                                               + ((slq ^ (rb[fj] & 7)) << 4));
#pragma unroll
                for (int i = 0; i < 4; ++i)
#pragma unroll
                    for (int fj = 0; fj < 4; ++fj)
                        acc[i][fj] = __builtin_amdgcn_mfma_f32_16x16x32_bf16(
                            af[i], bfr[fj], acc[i][fj], 0, 0, 0);
            }
        }
    }

    // epilogue: BN + PReLU, fp32 store. wave w -> pixel row y0+w.
    const float alpha = (mod ? prd : prr)[0];
    float* outp = conv + (long)mb * 256 * NPIX;
    const int nbase = (y0 + w) * 64;
#pragma unroll
    for (int i = 0; i < 4; ++i) {
#pragma unroll
        for (int r = 0; r < 4; ++r) {
            int oc = m0 + 16 * i + quad * 4 + r;
            float sc = scA[mod * 256 + oc];
            float sh = shB[mod * 256 + oc];
            float* orow = outp + (long)oc * NPIX;
#pragma unroll
            for (int fj = 0; fj < 4; ++fj) {
                int n = nbase + 16 * fj + l15;
                float y = acc[i][fj][r] * sc + sh;
                y = (y > 0.f) ? y : alpha * y;
                orow[n] = y;
            }
        }
    }
}

// ---------------------------------------------------------------------------
// 1x1-projection MFMA GEMM. mode 0 output scaled by oscale (log2e for Q).
// ---------------------------------------------------------------------------
__global__ __launch_bounds__(256)
void proj_mfma(const __bf16* __restrict__ Wb, int mstride,
               const __bf16* __restrict__ Bt,
               const float* __restrict__ bias_r, const float* __restrict__ bias_d,
               __bf16* __restrict__ dstT, __bf16* __restrict__ dstV,
               float* __restrict__ dstU,
               const float* __restrict__ resid_r, const float* __restrict__ resid_d,
               int mode, float oscale)
{
    __shared__ __bf16 As[128 * 32];
    __shared__ __bf16 Bs[128 * 32];

    const int t = threadIdx.x;
    const int n0 = blockIdx.x * 128;
    const int m0 = blockIdx.y * 128;
    const int mb = blockIdx.z;
    const int mod = mb >> 1, b = mb & 1;

    const __bf16* Am = Wb + (long)mod * mstride;
    const __bf16* Bm = Bt + (long)mb * (NPIX * 256);
    const float* bias = mod ? bias_d : bias_r;

    const int rowa = t >> 2, c16 = t & 3;
    char* ldsA0 = (char*)As + (t >> 6) * 1024;
    char* ldsA1 = ldsA0 + 4096;
    char* ldsB0 = (char*)Bs + (t >> 6) * 1024;
    char* ldsB1 = ldsB0 + 4096;
    const __bf16* srcA = Am + (long)(m0 + rowa) * 256 + c16 * 8;
    const __bf16* srcB = Bm + (long)(n0 + rowa) * 256 + c16 * 8;

    const int lane = t & 63, quad = lane >> 4, l15 = lane & 15, w = t >> 6;
    const int mw = (w >> 1) * 64, nw = (w & 1) * 64;
    const char* abase = (const char*)As + (mw + l15) * 64 + quad * 16;
    const char* bbase = (const char*)Bs + (nw + l15) * 64 + quad * 16;

    f32x4 acc[4][4];
#pragma unroll
    for (int i = 0; i < 4; ++i)
#pragma unroll
        for (int j = 0; j < 4; ++j) acc[i][j] = (f32x4)0.f;

    for (int kc = 0; kc < 256; kc += 32) {
        load_lds16(srcA + kc, ldsA0);
        load_lds16(srcA + kc + 16384, ldsA1);
        load_lds16(srcB + kc, ldsB0);
        load_lds16(srcB + kc + 16384, ldsB1);
        __syncthreads();

        bf16x8 af[4], bfr[4];
#pragma unroll
        for (int i = 0; i < 4; ++i) af[i]  = *(const bf16x8*)(abase + i * 1024);
#pragma unroll
        for (int j = 0; j < 4; ++j) bfr[j] = *(const bf16x8*)(bbase + j * 1024);
#pragma unroll
        for (int i = 0; i < 4; ++i)
#pragma unroll
            for (int j = 0; j < 4; ++j)
                acc[i][j] = __builtin_amdgcn_mfma_f32_16x16x32_bf16(
                    af[i], bfr[j], acc[i][j], 0, 0, 0);
        __syncthreads();
    }

    if (mode == 0) {
        if (mw == 0) {
            __bf16* dbase = dstT + (long)mb * (NPIX * 32);
#pragma unroll
            for (int fi = 0; fi < 2; ++fi)
#pragma unroll
                for (int r = 0; r < 4; ++r) {
                    int oc = 16 * fi + quad * 4 + r;
                    float bi = bias[oc];
#pragma unroll
                    for (int fj = 0; fj < 4; ++fj) {
                        int n = n0 + nw + 16 * fj + l15;
                        dbase[(long)n * 32 + oc] = f2b((acc[fi][fj][r] + bi) * oscale);
                    }
                }
        }
    } else if (mode == 1) {
        __bf16* dv = dstV + (long)mb * (256 * NPIX);
#pragma unroll
        for (int fi = 0; fi < 4; ++fi)
#pragma unroll
            for (int r = 0; r < 4; ++r) {
                int c = m0 + mw + 16 * fi + quad * 4 + r;
                float bi = bias[c];
                __bf16* row = dv + (long)c * NPIX;
#pragma unroll
                for (int fj = 0; fj < 4; ++fj) {
                    int n = n0 + nw + 16 * fj + l15;
                    row[n] = f2b(acc[fi][fj][r] + bi);
                }
            }
    } else {
        float* du = dstU + (long)mod * 4194304 + (long)b * 2097152;
        const float* rs = (mod ? resid_d : resid_r) + (long)b * 2097152;
#pragma unroll
        for (int fi = 0; fi < 4; ++fi)
#pragma unroll
            for (int r = 0; r < 4; ++r) {
                int oc = m0 + mw + 16 * fi + quad * 4 + r;
                float bi = bias[oc];
                const float* rrow = rs + (long)oc * NPIX;
                float* orow = du + (long)oc * NPIX;
#pragma unroll
                for (int fj = 0; fj < 4; ++fj) {
                    int n = n0 + nw + 16 * fj + l15;
                    orow[n] = acc[fi][fj][r] + bi + rrow[n];
                }
            }
    }
}

// ---------------------------------------------------------------------------
// Online MFMA row stats over a j-SEGMENT [seg*1024, +1024): partial (m, l)
// in log2 domain, single pass. grid (32 i, 4 mbo, 4 seg) = 512 blocks.
// ---------------------------------------------------------------------------
__global__ __launch_bounds__(256)
void attn_stats_mfma(const __bf16* __restrict__ Qt, const __bf16* __restrict__ Kt,
                     float* __restrict__ rmp, float* __restrict__ rlp)
{
    __shared__ __bf16 Qs[128 * 32];
    __shared__ __bf16 Ks[128 * 32];
    __shared__ float redm[2][128];
    __shared__ float redl[2][128];

    const int t  = threadIdx.x;
    const int i0 = blockIdx.x * 128;
    const int mbo = blockIdx.y;
    const int o  = mbo >> 1, b = mbo & 1;
    const int seg = blockIdx.z;
    const int jbase = seg * 1024;
    const int mbK = o * 2 + b, mbQ = (1 - o) * 2 + b;

    const __bf16* Qg = Qt + (long)mbQ * 131072;
    const __bf16* Kg = Kt + (long)mbK * 131072;

    const int lane = t & 63, quad = lane >> 4, l15 = lane & 15, w = t >> 6;
    const int mS = (w >> 1) * 64;
    const int nS = (w & 1) * 64;

    load_lds16((const char*)Qg + (long)i0 * 64 + t * 16, (char*)Qs + w * 1024);
    load_lds16((const char*)Qg + (long)i0 * 64 + 4096 + t * 16,
               (char*)Qs + 4096 + w * 1024);
    __syncthreads();

    bf16x8 qa[4];
#pragma unroll
    for (int fi = 0; fi < 4; ++fi)
        qa[fi] = *(const bf16x8*)((const char*)Qs + (mS + 16 * fi + l15) * 64 + quad * 16);

    const f32x4 zero4 = (f32x4)0.f;
    float m_t[16], l_t[16];
#pragma unroll
    for (int e = 0; e < 16; ++e) { m_t[e] = -3.0e38f; l_t[e] = 0.f; }

    for (int j0 = jbase; j0 < jbase + 1024; j0 += 128) {
        __syncthreads();
        load_lds16((const char*)Kg + (long)j0 * 64 + t * 16, (char*)Ks + w * 1024);
        load_lds16((const char*)Kg + (long)j0 * 64 + 4096 + t * 16,
                   (char*)Ks + 4096 + w * 1024);
        __syncthreads();

        bf16x8 kb[4];
#pragma unroll
        for (int fj = 0; fj < 4; ++fj)
            kb[fj] = *(const bf16x8*)((const char*)Ks + (nS + 16 * fj + l15) * 64 + quad * 16);
#pragma unroll
        for (int fi = 0; fi < 4; ++fi) {
            f32x4 sf[4];
#pragma unroll
            for (int fj = 0; fj < 4; ++fj)
                sf[fj] = __builtin_amdgcn_mfma_f32_16x16x32_bf16(qa[fi], kb[fj], zero4, 0, 0, 0);
#pragma unroll
            for (int r = 0; r < 4; ++r) {
                int e = fi * 4 + r;
                float a = fmaxf(fmaxf(sf[0][r], sf[1][r]), fmaxf(sf[2][r], sf[3][r]));
                float nm = fmaxf(m_t[e], a);
                float s = exp2f(sf[0][r] - nm) + exp2f(sf[1][r] - nm)
                        + exp2f(sf[2][r] - nm) + exp2f(sf[3][r] - nm);
                l_t[e] = l_t[e] * exp2f(m_t[e] - nm) + s;
                m_t[e] = nm;
            }
        }
    }

    // merge across the 16 l15 lanes (each holds a disjoint j-subset)
#pragma unroll
    for (int d = 1; d < 16; d <<= 1)
#pragma unroll
        for (int e = 0; e < 16; ++e) {
            float om = __shfl_xor(m_t[e], d, 64);
            float ol = __shfl_xor(l_t[e], d, 64);
            float nm = fmaxf(m_t[e], om);
            l_t[e] = l_t[e] * exp2f(m_t[e] - nm) + ol * exp2f(om - nm);
            m_t[e] = nm;
        }
    if (l15 == 0) {
#pragma unroll
        for (int fi = 0; fi < 4; ++fi)
#pragma unroll
            for (int r = 0; r < 4; ++r) {
                redm[w & 1][mS + 16 * fi + quad * 4 + r] = m_t[fi * 4 + r];
                redl[w & 1][mS + 16 * fi + quad * 4 + r] = l_t[fi * 4 + r];
            }
    }
    __syncthreads();
    if (t < 128) {
        float m0 = redm[0][t], m1 = redm[1][t];
        float l0 = redl[0][t], l1 = redl[1][t];
        float m = fmaxf(m0, m1);
        float l = l0 * exp2f(m0 - m) + l1 * exp2f(m1 - m);
        rmp[seg * 16384 + mbo * 4096 + i0 + t] = m;
        rlp[seg * 16384 + mbo * 4096 + i0 + t] = l;
    }
}

// ---------------------------------------------------------------------------
// Merge 4-segment stats: m = max, rl = 1/sum(l_s * 2^(m_s-m)). grid 64x256.
// ---------------------------------------------------------------------------
__global__ __launch_bounds__(256)
void stats_merge(const float* __restrict__ rmp, const float* __restrict__ rlp,
                 float* __restrict__ rmb, float* __restrict__ rlb)
{
    int idx = blockIdx.x * 256 + threadIdx.x;
    float m = rmp[idx];
#pragma unroll
    for (int s = 1; s < 4; ++s) m = fmaxf(m, rmp[s * 16384 + idx]);
    float l = 0.f;
#pragma unroll
    for (int s = 0; s < 4; ++s)
        l += rlp[s * 16384 + idx] * exp2f(rmp[s * 16384 + idx] - m);
    rmb[idx] = m;
    rlb[idx] = 1.f / l;
}

// ---------------------------------------------------------------------------
// Fused MFMA PV over a j-SEGMENT, full c=256 per block (S computed ONCE).
// i-tile 64. grid (64 i, 2 seg, 4 mb) = 512 blocks, 2/CU, 48KB LDS.
// Ps[64][64] XOR-swizzled (byte ^= (i&12)<<3): conflict-free store AND read.
// rl applied once in epilogue. P = exp2(S - m) (Qt pre-scaled by log2e).
// ---------------------------------------------------------------------------
__global__ __launch_bounds__(256)
void attn_pv_mfma(const __bf16* __restrict__ Qt, const __bf16* __restrict__ Kt,
                  const __bf16* __restrict__ Vb,
                  float* __restrict__ part0, float* __restrict__ part1,
                  const float* __restrict__ rmb, const float* __restrict__ rlb)
{
    __shared__ __bf16 Qs[64 * 32];        // 4KB  [i][32ch]
    __shared__ __bf16 Ks[64 * 32];        // 4KB  [j][32ch]
    __shared__ __bf16 Vs[2 * 256 * 32];   // 32KB [ks][c][32j]
    __shared__ __bf16 Ps[64 * 64];        // 8KB  [i][64j] swizzled

    const int t  = threadIdx.x;
    const int i0 = blockIdx.x * 64;
    const int seg = blockIdx.y;
    const int mb = blockIdx.z;
    const int o  = mb >> 1, b = mb & 1;
    const int mbK = mb, mbQ = (1 - o) * 2 + b;
    const int jbase = seg * 2048;

    const __bf16* Qg = Qt + (long)mbQ * 131072;
    const __bf16* Kg = Kt + (long)mbK * 131072;
    const __bf16* Vg = Vb + (long)mbK * 1048576;
    const float* rm = rmb + mb * 4096;
    const float* rl = rlb + mb * 4096;

    const int lane = t & 63, quad = lane >> 4, l15 = lane & 15, w = t >> 6;
    const int iS = w * 16;        // this wave's S row block
    const int cw = w * 64;        // this wave's PV c block

    load_lds16((const char*)Qg + (long)i0 * 64 + t * 16, (char*)Qs + w * 1024);

    float mlv[4], rlv[4];
#pragma unroll
    for (int r = 0; r < 4; ++r) mlv[r] = rm[i0 + iS + quad * 4 + r];
#pragma unroll
    for (int fj = 0; fj < 4; ++fj) rlv[fj] = rl[i0 + 16 * fj + l15];

    f32x4 acc[4][4];
#pragma unroll
    for (int i = 0; i < 4; ++i)
#pragma unroll
        for (int j = 0; j < 4; ++j) acc[i][j] = (f32x4)0.f;
    const f32x4 zero4 = (f32x4)0.f;

    __syncthreads();
    const bf16x8 qa = *(const bf16x8*)((const char*)Qs + (iS + l15) * 64 + quad * 16);

    const int clv = w * 16 + (lane >> 2);   // V staging: c within 64-group
    const int jb8 = (lane & 3) * 8;         // V staging: j offset

    for (int j0 = jbase; j0 < jbase + 2048; j0 += 64) {
        __syncthreads();                    // prev-step consumers done
        load_lds16((const char*)Kg + (long)j0 * 64 + t * 16, (char*)Ks + w * 1024);
        __syncthreads();                    // K ready (only K in flight)

        // issue V loads now; latency hides under S + P (drained at next barrier)
#pragma unroll
        for (int ii = 0; ii < 8; ++ii) {
            int ks = ii >> 2;
            int c = (ii & 3) * 64 + clv;
            load_lds16((const char*)Vg + (long)c * 8192 + (long)(j0 + ks * 32 + jb8) * 2,
                       (char*)Vs + ii * 4096 + w * 1024);
        }

        // S = Q K^T for rows [iS,iS+16), cols [0,64)  (one mfma per 16 cols)
        f32x4 sA[4];
#pragma unroll
        for (int fj = 0; fj < 4; ++fj) {
            bf16x8 kb = *(const bf16x8*)((const char*)Ks + (16 * fj + l15) * 64 + quad * 16);
            sA[fj] = __builtin_amdgcn_mfma_f32_16x16x32_bf16(qa, kb, zero4, 0, 0, 0);
        }
        // P = exp2(S - m) -> swizzled Ps (conflict-free b16 stores)
#pragma unroll
        for (int fj = 0; fj < 4; ++fj)
#pragma unroll
            for (int r = 0; r < 4; ++r) {
                int il = iS + quad * 4 + r;
                int boff = (il * 128 + (16 * fj + l15) * 2) ^ ((il & 12) << 3);
                *(__bf16*)((char*)Ps + boff) = f2b(exp2f(sA[fj][r] - mlv[r]));
            }
        __syncthreads();                    // P visible, V staged

#pragma unroll
        for (int ks = 0; ks < 2; ++ks) {
            bf16x8 va[4], pb[4];
#pragma unroll
            for (int fi = 0; fi < 4; ++fi)
                va[fi] = *(const bf16x8*)((const char*)Vs + ks * 16384 +
                                          (cw + 16 * fi + l15) * 64 + quad * 16);
#pragma unroll
            for (int fj = 0; fj < 4; ++fj) {
                int ip = 16 * fj + l15;
                int boff = (ip * 128 + ks * 64 + quad * 16) ^ ((ip & 12) << 3);
                pb[fj] = *(const bf16x8*)((const char*)Ps + boff);
            }
#pragma unroll
            for (int fi = 0; fi < 4; ++fi)
#pragma unroll
                for (int fj = 0; fj < 4; ++fj)
                    acc[fi][fj] = __builtin_amdgcn_mfma_f32_16x16x32_bf16(
                        va[fi], pb[fj], acc[fi][fj], 0, 0, 0);
        }
    }

    // partial store, rl folded here (acc * 1/l)
    float* pg = (seg ? part1 : part0) + (long)mb * 1048576;
#pragma unroll
    for (int fi = 0; fi < 4; ++fi) {
#pragma unroll
        for (int r = 0; r < 4; ++r) {
            int c = cw + 16 * fi + quad * 4 + r;
            float* zr = pg + (long)c * 4096;
#pragma unroll
            for (int fj = 0; fj < 4; ++fj)
                zr[i0 + 16 * fj + l15] = acc[fi][fj][r] * rlv[fj];
        }
    }
}

// ---------------------------------------------------------------------------
// z = gamma*(part0+part1) + conv, transposed bf16 store to Zt[pix][256].
// grid (128, 8, 4).
// ---------------------------------------------------------------------------
__global__ __launch_bounds__(256)
void zred_t(const float* __restrict__ p0, const float* __restrict__ p1,
            const float* __restrict__ convb, __bf16* __restrict__ Zt,
            const float* __restrict__ g_r, const float* __restrict__ g_d)
{
    __shared__ float tile[32][33];
    const int t = threadIdx.x;
    const int pix0 = blockIdx.x * 32;
    const int c0 = blockIdx.y * 32;
    const int mb = blockIdx.z;
    const int o = mb >> 1;
    const float gamma = (o ? g_d : g_r)[0];
    const long base = (long)mb * 1048576;

    int i = t >> 3, j4 = (t & 7) * 4;
    long row = base + (long)(c0 + i) * 4096 + pix0 + j4;
    float4 a = *(const float4*)&p0[row];
    float4 b = *(const float4*)&p1[row];
    float4 cv = *(const float4*)&convb[row];
    tile[i][j4 + 0] = gamma * (a.x + b.x) + cv.x;
    tile[i][j4 + 1] = gamma * (a.y + b.y) + cv.y;
    tile[i][j4 + 2] = gamma * (a.z + b.z) + cv.z;
    tile[i][j4 + 3] = gamma * (a.w + b.w) + cv.w;
    __syncthreads();
    int j = t >> 3, i4 = (t & 7) * 4;
    bf16x4 oq;
    oq.x = f2b(tile[i4 + 0][j]); oq.y = f2b(tile[i4 + 1][j]);
    oq.z = f2b(tile[i4 + 2][j]); oq.w = f2b(tile[i4 + 3][j]);
    *(bf16x4*)&Zt[(long)mb * NPIX * 256 + (long)(pix0 + j) * 256 + c0 + i4] = oq;
}

// ---------------------------------------------------------------------------
// Host launcher
// ---------------------------------------------------------------------------
// ws layout (float slots):
//   conv fp32 [4mb][256][4096] @ 0           (4,194,304)
//   part0 fp32 [4mb][256][4096]@ 4,194,304   (4,194,304)
//     (first 131,072 floats double as rmp/rlp [4seg][4][4096] scratch,
//      consumed by stats_merge BEFORE attn_pv writes part0)
//   rmb  [4mbo][4096]          @ 8,388,608   (16,384)
//   rlb                         @ 8,404,992  (16,384)
//   (old rmp/rlp slots unused)  @ 8,421,376  (65,536)
//   scA  [2][256]              @ 8,486,912   (512)
//   shB  [2][256]              @ 8,487,424   (512)
//   zrow (512 bf16)            @ 8,487,936   (256)
//   Wt   bf16 [2][9][256][512] @ 8,488,192   (1,179,648)
//   Xp   bf16 [4][4096][512]   @ 9,667,840   (4,194,304)  <- part1 after conv
//   Qt   bf16 [4][4096][32]    @ 13,862,144  (262,144)
//   Kt   bf16 [4][4096][32]    @ 14,124,288  (262,144)
//   Vbb  bf16 [4][256][4096]   @ 14,386,432  (2,097,152)
//   Ct   bf16 [4][4096][256]   @ 16,483,584  (2,097,152)
//   Zt   bf16 [4][4096][256]   @ 18,580,736  (2,097,152)
//   Wq   bf16 [2][128][256]    @ 20,677,888  (32,768)
//   Wk   bf16 [2][128][256]    @ 20,710,656  (32,768)
//   Wv   bf16 [2][256][256]    @ 20,743,424  (65,536)
//   Wu   bf16 [2][512][256]    @ 20,808,960  (131,072)
//   total 20,940,032 floats = 83.8 MiB
extern "C" void kernel_launch(void* const* d_in, const int* in_sizes, int n_in,
                              void* d_out, int out_size, void* d_ws, size_t ws_size,
                              hipStream_t stream)
{
    const float* in_rgb = (const float*)d_in[0];
    const float* in_dsm = (const float*)d_in[1];
    auto P = [&](int i) { return (const float*)d_in[i]; };

    float* ws    = (float*)d_ws;
    float* conv  = ws;
    float* part0 = ws + 4194304;
    float* rmb   = ws + 8388608;
    float* rlb   = ws + 8404992;
    float* rmp   = part0;            // [4][4][4096] scratch, dead before pv
    float* rlp   = part0 + 65536;
    float* scA   = ws + 8486912;
    float* shB   = ws + 8487424;
    __bf16* zrow = (__bf16*)(ws + 8487936);
    __bf16* Wt   = (__bf16*)(ws + 8488192);
    __bf16* Xp   = (__bf16*)(ws + 9667840);
    float*  part1 = ws + 9667840;            // aliases Xp (dead after conv)
    __bf16* Qt   = (__bf16*)(ws + 13862144);
    __bf16* Kt   = (__bf16*)(ws + 14124288);
    __bf16* Vbb  = (__bf16*)(ws + 14386432);
    __bf16* Ct   = (__bf16*)(ws + 16483584);
    __bf16* Zt   = (__bf16*)(ws + 18580736);
    __bf16* Wq   = (__bf16*)(ws + 20677888);
    __bf16* Wk   = (__bf16*)(ws + 20710656);
    __bf16* Wv   = (__bf16*)(ws + 20743424);
    __bf16* Wu   = (__bf16*)(ws + 20808960);

    // prep
    prep_w<<<2307, 256, 0, stream>>>(
        P(2), P(18), P(3), P(4), P(5), P(6), P(7),
        P(19), P(20), P(21), P(22), P(23),
        Wt, scA, shB, zrow);
    prep_gw<<<512, 256, 0, stream>>>(
        P(9), P(25), P(11), P(27), P(13), P(29), P(15), P(31),
        Wq, Wk, Wv, Wu);
    xpose<<<dim3(128, 16, 4), 256, 0, stream>>>(in_rgb, in_dsm, Xp);

    // conv3x3 + BN + PReLU (v3: halo, 256 blocks = 1/CU, counted vmcnt)
    conv_mfma<<<dim3(16, 4, 4), 256, 0, stream>>>(
        Wt, Xp, zrow, scA, shB, P(8), P(24), conv);
    t256<<<dim3(128, 8, 4), 256, 0, stream>>>(conv, Ct);

    // q/k/v projections (Q pre-scaled by log2e -> exp2 softmax domain)
    proj_mfma<<<dim3(32, 1, 4), 256, 0, stream>>>(
        Wq, 32768, Ct, P(10), P(26), Qt, nullptr, nullptr, nullptr, nullptr,
        0, 1.4426950408889634f);
    proj_mfma<<<dim3(32, 1, 4), 256, 0, stream>>>(
        Wk, 32768, Ct, P(12), P(28), Kt, nullptr, nullptr, nullptr, nullptr,
        0, 1.0f);
    proj_mfma<<<dim3(32, 2, 4), 256, 0, stream>>>(
        Wv, 65536, Ct, P(14), P(30), nullptr, Vbb, nullptr, nullptr, nullptr,
        1, 1.0f);

    // online softmax stats (j-split x4, 512 blocks) + merge
    attn_stats_mfma<<<dim3(32, 4, 4), 256, 0, stream>>>(Qt, Kt, rmp, rlp);
    stats_merge<<<64, 256, 0, stream>>>(rmp, rlp, rmb, rlb);

    // fused PV (j-split x2 -> raw partials; part1 overwrites dead Xp)
    attn_pv_mfma<<<dim3(64, 2, 4), 256, 0, stream>>>(
        Qt, Kt, Vbb, part0, part1, rmb, rlb);

    // z = gamma*(p0+p1)+conv, transpose + bf16 -> Zt
    zred_t<<<dim3(128, 8, 4), 256, 0, stream>>>(
        part0, part1, conv, Zt, P(17), P(33));

    // up projection + input residual -> fp32 out
    proj_mfma<<<dim3(32, 4, 4), 256, 0, stream>>>(
        Wu, 131072, Zt, P(16), P(32), nullptr, nullptr, (float*)d_out,
        in_rgb, in_dsm, 2, 1.0f);
}